// Round 7
// baseline (7012.594 us; speedup 1.0000x reference)
//
#include <hip/hip_runtime.h>
#include <math.h>

typedef unsigned short u16;
typedef __attribute__((ext_vector_type(4))) unsigned short u16x4;
typedef __attribute__((ext_vector_type(8))) unsigned short u16x8;
typedef __attribute__((ext_vector_type(8))) short short8;   // MFMA A/B frag (8 bf16)
typedef __attribute__((ext_vector_type(4))) float f32x4;    // MFMA C/D frag

#define BB 8
#define CC 256
#define LL 77
#define HW 16384    // 128*128
#define XROW 520    // XT row stride in ch (513 padded to 8-multiple)

__device__ __forceinline__ float bf2f(u16 h) {
  return __uint_as_float(((unsigned)h) << 16);
}
__device__ __forceinline__ u16 f2bf(float f) {   // round-to-nearest-even
  unsigned u = __float_as_uint(f);
  unsigned r = (u + 0x7fffu + ((u >> 16) & 1u)) >> 16;
  return (u16)r;
}

// ---------------- workspace layout (BYTE offsets) ----------------
static const size_t OFF_XT    = 0;
static const size_t OFF_B     = 136314880;
static const size_t OFF_GVECB = 630784;          // relative to OFF_B
static const size_t OFF_GNSUM = 203423744;
static const size_t WS_BYTES_NEEDED = 203425792;  // ~194.0 MiB
// Region-A reuse offsets (absolute):
static const size_t OFF_Y2T = 0;
static const size_t OFF_GA  = 16777216;
static const size_t OFF_GB  = 16785408;
static const size_t OFF_Y3  = 16793600;
// d_out scratch: wt1 then wt2 (dead until final upsample)
static const size_t WT1_BYTES = 9u * 256u * 544u * 2u;   // 2,506,752 (16B aligned)

// ---------------- diagnostic fill (only if ws too small) ----------------
__global__ __launch_bounds__(256) void fill_kernel(float* __restrict__ out,
                                                   int n, float v) {
  int i = blockIdx.x * 256 + threadIdx.x;
  if (i < n) out[i] = v;
}

__global__ __launch_bounds__(512) void zero_gnsum(float* __restrict__ g) {
  g[threadIdx.x] = 0.f;
}

// ---------------- weight transpose: w[oc][ic][3][3] f32 -> wt[kk][oc][icpad] bf16
__global__ __launch_bounds__(256) void prep_wt(
    const float* __restrict__ w, u16* __restrict__ wt,
    int OC, int ICSRC, int ICPAD, int total) {
  int idx = blockIdx.x * 256 + threadIdx.x;
  if (idx >= total) return;
  int ic = idx % ICPAD;
  int oc = (idx / ICPAD) % OC;
  int kk = idx / (ICPAD * OC);
  float v = 0.f;
  if (ic < ICSRC) v = w[((size_t)oc * ICSRC + ic) * 9 + kk];
  wt[idx] = f2bf(v);
}

// ---------------- conv1: 3->64, stride 2, 512->256, relu (f32 in, bf16 [c][p] out)
__global__ __launch_bounds__(256) void conv1_kernel(
    const float* __restrict__ in, const float* __restrict__ w,
    const float* __restrict__ bias, u16* __restrict__ out) {
  constexpr int IC = 3, WIN = 512, WOUT = 256, OC = 64;
  constexpr int TPR = WOUT / 4;
  __shared__ float wl[IC * 9 * 2];
  const int tid = threadIdx.x;
  const int oc0 = blockIdx.y * 2;
  const int b = blockIdx.z;
  for (int i = tid; i < IC * 9 * 2; i += 256) {
    int j = (i >= IC * 9) ? 1 : 0;
    int t = i - j * IC * 9;
    wl[t * 2 + j] = w[(size_t)(oc0 + j) * IC * 9 + t];
  }
  __syncthreads();
  const int t = tid % TPR;
  const int oh = blockIdx.x * (256 / TPR) + tid / TPR;
  const int ow0 = t * 4;
  float acc[2][4];
  #pragma unroll
  for (int j = 0; j < 2; ++j) {
    float bb = bias[oc0 + j];
    #pragma unroll
    for (int i = 0; i < 4; ++i) acc[j][i] = bb;
  }
  for (int ic = 0; ic < IC; ++ic) {
    const float* plane = in + ((size_t)b * IC + ic) * ((size_t)WIN * WIN);
    #pragma unroll
    for (int kh = 0; kh < 3; ++kh) {
      int ih = 2 * oh + kh - 1;
      if ((unsigned)ih >= (unsigned)WIN) continue;
      const float* row = plane + (size_t)ih * WIN;
      const int base = ow0 * 2;
      float v[9];
      float4 a = *reinterpret_cast<const float4*>(row + base);
      float4 c4 = *reinterpret_cast<const float4*>(row + base + 4);
      v[1] = a.x; v[2] = a.y; v[3] = a.z; v[4] = a.w;
      v[5] = c4.x; v[6] = c4.y; v[7] = c4.z; v[8] = c4.w;
      v[0] = (base > 0) ? row[base - 1] : 0.f;
      const float2* wp = reinterpret_cast<const float2*>(wl) + (ic * 3 + kh) * 3;
      float2 w0 = wp[0], w1 = wp[1], w2 = wp[2];
      #pragma unroll
      for (int i = 0; i < 4; ++i) {
        acc[0][i] += v[2 * i] * w0.x + v[2 * i + 1] * w1.x + v[2 * i + 2] * w2.x;
        acc[1][i] += v[2 * i] * w0.y + v[2 * i + 1] * w1.y + v[2 * i + 2] * w2.y;
      }
    }
  }
  const int p = oh * WOUT + ow0;
  #pragma unroll
  for (int j = 0; j < 2; ++j) {
    u16x4 o;
    #pragma unroll
    for (int i = 0; i < 4; ++i) o[i] = f2bf(fmaxf(acc[j][i], 0.f));
    *reinterpret_cast<u16x4*>(out + ((size_t)b * OC + oc0 + j) * (WOUT * WOUT) + p) = o;
  }
}

// ---------------- conv2: 64->256, stride 2, relu, + inline pos; writes XT[p][oc]
__global__ __launch_bounds__(256) void conv2_kernel(
    const u16* __restrict__ x1, const float* __restrict__ w,
    const float* __restrict__ bias,
    const float* __restrict__ sp1_w, const float* __restrict__ sp1_b,
    const float* __restrict__ sp2_w, const float* __restrict__ sp2_b,
    u16* __restrict__ xt) {
  constexpr int IC = 64, WIN = 256;
  __shared__ float wl[IC * 9 * 2];
  __shared__ float s1w[128], s1b[64], s2w[128];
  const int tid = threadIdx.x;
  const int oc0 = blockIdx.y * 2;
  const int b = blockIdx.z;
  for (int i = tid; i < IC * 9 * 2; i += 256) {
    int j = (i >= IC * 9) ? 1 : 0;
    int t = i - j * IC * 9;
    wl[t * 2 + j] = w[(size_t)(oc0 + j) * IC * 9 + t];
  }
  if (tid < 128) s1w[tid] = sp1_w[tid];
  if (tid < 64) s1b[tid] = sp1_b[tid];
  if (tid < 128) s2w[tid] = sp2_w[(size_t)(oc0 + (tid >> 6)) * 64 + (tid & 63)];
  __syncthreads();
  const int t = tid & 31;
  const int oh = blockIdx.x * 8 + (tid >> 5);
  const int ow0 = t * 4;
  float acc[2][4];
  #pragma unroll
  for (int j = 0; j < 2; ++j) {
    float bb = bias[oc0 + j];
    #pragma unroll
    for (int i = 0; i < 4; ++i) acc[j][i] = bb;
  }
  for (int ic = 0; ic < IC; ++ic) {
    const u16* plane = x1 + ((size_t)b * IC + ic) * ((size_t)WIN * WIN);
    #pragma unroll
    for (int kh = 0; kh < 3; ++kh) {
      int ih = 2 * oh + kh - 1;
      if ((unsigned)ih >= (unsigned)WIN) continue;
      const u16* row = plane + (size_t)ih * WIN;
      const int base = ow0 * 2;
      float v[9];
      u16x8 a = *reinterpret_cast<const u16x8*>(row + base);
      #pragma unroll
      for (int i2 = 0; i2 < 8; ++i2) v[1 + i2] = bf2f(a[i2]);
      v[0] = (base > 0) ? bf2f(row[base - 1]) : 0.f;
      const float2* wp = reinterpret_cast<const float2*>(wl) + (ic * 3 + kh) * 3;
      float2 w0 = wp[0], w1 = wp[1], w2 = wp[2];
      #pragma unroll
      for (int i = 0; i < 4; ++i) {
        acc[0][i] += v[2 * i] * w0.x + v[2 * i + 1] * w1.x + v[2 * i + 2] * w2.x;
        acc[1][i] += v[2 * i] * w0.y + v[2 * i + 1] * w1.y + v[2 * i + 2] * w2.y;
      }
    }
  }
  // epilogue: relu(conv) + pos(oc, px), scatter into XT[p][oc0..oc0+1]
  const float yy = -1.f + oh * (2.f / 127.f);
  const float sb0 = sp2_b[oc0], sb1 = sp2_b[oc0 + 1];
  u16* xb = xt + (size_t)b * HW * XROW;
  #pragma unroll
  for (int i = 0; i < 4; ++i) {
    float xxv = -1.f + (ow0 + i) * (2.f / 127.f);
    float pa = sb0, pb = sb1;
    #pragma unroll 8
    for (int h = 0; h < 64; ++h) {
      float hid = fmaxf(s1w[2 * h] * xxv + s1w[2 * h + 1] * yy + s1b[h], 0.f);
      pa = fmaf(s2w[h], hid, pa);
      pb = fmaf(s2w[64 + h], hid, pb);
    }
    float r0 = fmaxf(acc[0][i], 0.f) + pa;
    float r1 = fmaxf(acc[1][i], 0.f) + pb;
    int p = oh * 128 + ow0 + i;
    unsigned pk = (unsigned)f2bf(r0) | ((unsigned)f2bf(r1) << 16);
    *reinterpret_cast<unsigned*>(xb + (size_t)p * XROW + oc0) = pk;
  }
}

// ---------------- token pipeline: proj -> gate -> l2norm (f32 out) ----------
__global__ __launch_bounds__(256) void token_kernel(
    const float* __restrict__ tok512, const float* __restrict__ proj_w,
    const float* __restrict__ proj_b, const float* __restrict__ gate_w,
    const float* __restrict__ gate_b, float* __restrict__ tok_out) {
  __shared__ float t512[512];
  __shared__ float prj[256];
  __shared__ float red[4];
  int bl = blockIdx.x;
  int c = threadIdx.x;
  const float* trow = tok512 + (size_t)bl * 512;
  t512[c] = trow[c];
  t512[c + 256] = trow[c + 256];
  __syncthreads();
  float acc = proj_b[c];
  #pragma unroll 4
  for (int k = 0; k < 512; ++k) acc = fmaf(t512[k], proj_w[k * 256 + c], acc);
  prj[c] = acc;
  __syncthreads();
  float acc2 = gate_b[c];
  #pragma unroll 4
  for (int k = 0; k < 256; ++k) acc2 = fmaf(prj[k], gate_w[k * 256 + c], acc2);
  float g = 1.f / (1.f + __expf(-acc2));
  float tv = g * acc;
  float ss = tv * tv;
  #pragma unroll
  for (int off = 1; off < 64; off <<= 1) ss += __shfl_xor(ss, off);
  if ((c & 63) == 0) red[c >> 6] = ss;
  __syncthreads();
  float tot = red[0] + red[1] + red[2] + red[3];
  tok_out[(size_t)bl * 256 + c] = tv * (1.f / fmaxf(sqrtf(tot), 1e-12f));
}

// ---------------- gvec ----------------
__global__ __launch_bounds__(256) void gvec_kernel(
    const float* __restrict__ tok, const int* __restrict__ tokens,
    float* __restrict__ gvec) {
  __shared__ float red[4];
  int b = blockIdx.x, c = threadIdx.x;
  float s = 0.f;
  for (int l = 0; l < LL; ++l) {
    if (tokens[b * LL + l] != 0) s += tok[((size_t)b * LL + l) * 256 + c];
  }
  float ss = s * s;
  #pragma unroll
  for (int off = 1; off < 64; off <<= 1) ss += __shfl_xor(ss, off);
  if ((c & 63) == 0) red[c >> 6] = ss;
  __syncthreads();
  float tot = red[0] + red[1] + red[2] + red[3];
  gvec[b * 256 + c] = s * (1.f / fmaxf(sqrtf(tot), 1e-12f));
}

// ---------------- attn: full-64B-line IO, no VGPR cap (s[77] stays in regs) --
// reads XT img (ch 0..255), writes ctx (256..511), sim+pad (512..519).
// c0 steps by 32: 4 consecutive u16x8 loads/stores = one full 64B line.
__global__ __launch_bounds__(256, 1) void attn_kernel(
    u16* __restrict__ xt, const float* __restrict__ tok,
    const int* __restrict__ tokens, const float* __restrict__ gvec) {
  __shared__ u16 ltok[LL * 256];   // bf16 tokens
  __shared__ float lgv[256];
  __shared__ u16 lval[LL + 3];
  const int tid = threadIdx.x;
  const int b = blockIdx.y;
  for (int slot = tid; slot < LL * 32; slot += 256) {
    int l = slot >> 5, cg = slot & 31;
    const float* tp = tok + ((size_t)b * LL + l) * 256 + cg * 8;
    float4 t0 = *reinterpret_cast<const float4*>(tp);
    float4 t1 = *reinterpret_cast<const float4*>(tp + 4);
    u16x8 v = {f2bf(t0.x), f2bf(t0.y), f2bf(t0.z), f2bf(t0.w),
               f2bf(t1.x), f2bf(t1.y), f2bf(t1.z), f2bf(t1.w)};
    *reinterpret_cast<u16x8*>(&ltok[l * 256 + cg * 8]) = v;
  }
  if (tid < LL) lval[tid] = (tokens[b * LL + tid] != 0) ? 1 : 0;
  lgv[tid] = gvec[b * 256 + tid];
  __syncthreads();
  const int p = blockIdx.x * 256 + tid;
  u16* xr = xt + ((size_t)b * HW + p) * XROW;
  float s[LL];
  #pragma unroll
  for (int l = 0; l < LL; ++l) s[l] = 0.f;
  float ssum = 0.f, simacc = 0.f;
  #pragma unroll 1
  for (int c0 = 0; c0 < 256; c0 += 32) {
    float x[32];
    #pragma unroll
    for (int q = 0; q < 4; ++q) {          // 4 consecutive 16B loads = 64B line
      u16x8 iv = *reinterpret_cast<const u16x8*>(xr + c0 + q * 8);
      #pragma unroll
      for (int k = 0; k < 8; ++k) x[q * 8 + k] = bf2f(iv[k]);
    }
    #pragma unroll
    for (int k = 0; k < 32; ++k) {
      ssum = fmaf(x[k], x[k], ssum);
      simacc = fmaf(x[k], lgv[c0 + k], simacc);
    }
    #pragma unroll
    for (int l = 0; l < LL; ++l) {
      const u16* tr = &ltok[l * 256 + c0];
      float a2 = s[l];
      #pragma unroll
      for (int q = 0; q < 4; ++q) {
        u16x8 tv = *reinterpret_cast<const u16x8*>(tr + q * 8);
        #pragma unroll
        for (int k = 0; k < 8; ++k) a2 = fmaf(x[q * 8 + k], bf2f(tv[k]), a2);
      }
      s[l] = a2;
    }
  }
  float invn = 1.f / fmaxf(sqrtf(ssum), 1e-12f);
  float sc = invn * 0.0625f;
  float m = -1e30f;
  #pragma unroll
  for (int l = 0; l < LL; ++l) {
    s[l] = lval[l] ? s[l] * sc : -10000.f;
    m = fmaxf(m, s[l]);
  }
  float sum = 0.f;
  #pragma unroll
  for (int l = 0; l < LL; ++l) {
    s[l] = __expf(s[l] - m);
    sum += s[l];
  }
  const float rs = 1.f / sum;
  #pragma unroll
  for (int l = 0; l < LL; ++l) s[l] *= rs;   // fold 1/sum into weights
  #pragma unroll 1
  for (int c0 = 0; c0 < 256; c0 += 32) {
    float a[32];
    #pragma unroll
    for (int k = 0; k < 32; ++k) a[k] = 0.f;
    #pragma unroll
    for (int l = 0; l < LL; ++l) {
      const u16* tr = &ltok[l * 256 + c0];
      float sl = s[l];
      #pragma unroll
      for (int q = 0; q < 4; ++q) {
        u16x8 tv = *reinterpret_cast<const u16x8*>(tr + q * 8);
        #pragma unroll
        for (int k = 0; k < 8; ++k) a[q * 8 + k] = fmaf(sl, bf2f(tv[k]), a[q * 8 + k]);
      }
    }
    #pragma unroll
    for (int q = 0; q < 4; ++q) {          // 4 consecutive 16B stores = 64B line
      u16x8 ov;
      #pragma unroll
      for (int k = 0; k < 8; ++k) ov[k] = f2bf(a[q * 8 + k]);
      *reinterpret_cast<u16x8*>(xr + 256 + c0 + q * 8) = ov;
    }
  }
  u16x8 sv = {f2bf(simacc * invn), 0, 0, 0, 0, 0, 0, 0};
  *reinterpret_cast<u16x8*>(xr + 512) = sv;   // sim + zero pad 513..519
}

// ---------------- MFMA conv 3x3 stride-1 on transposed input ----------------
template <int CHUNKS, int XR, int OC, int OCW, bool AFFINE, bool GNST, bool RELU,
          int OROW>
__global__ __launch_bounds__(256) void convT_mfma(
    const u16* __restrict__ xt, const u16* __restrict__ wt,
    const float* __restrict__ bias, const float* __restrict__ gA,
    const float* __restrict__ gB, float* __restrict__ gnsum,
    u16* __restrict__ outT) {
  constexpr int ICPAD = CHUNKS * 32;
  constexpr int OCB = 4 * OCW;
  constexpr int NOF = OCW / 16;
  __shared__ u16 lb[7920];   // 3*66*5 slots * 8 u16 = 15,840 B
  const int tid = threadIdx.x;
  const int lane = tid & 63;
  const int w = tid >> 6;
  const int oh = blockIdx.x >> 1;
  const int ow0 = (blockIdx.x & 1) << 6;
  const int oc0 = blockIdx.y * OCB + w * OCW;
  const int b = blockIdx.z;
  const int colA = lane & 15;
  const int g = lane >> 4;

  f32x4 acc[NOF][4];
  #pragma unroll
  for (int of = 0; of < NOF; ++of) {
    f32x4 bv;
    #pragma unroll
    for (int r = 0; r < 4; ++r) bv[r] = bias[oc0 + of * 16 + g * 4 + r];
    #pragma unroll
    for (int pf = 0; pf < 4; ++pf) acc[of][pf] = bv;
  }

  const u16* xtb = xt + (size_t)b * HW * XR;
  for (int ch = 0; ch < CHUNKS; ++ch) {
    __syncthreads();
    #pragma unroll
    for (int it = 0; it < 4; ++it) {
      int slot = it * 256 + tid;
      if (slot < 792) {
        int icg = slot & 3;
        int rc = slot >> 2;
        int col = rc % 66;
        int row = rc / 66;
        int ih = oh + row - 1;
        int ip = ow0 - 1 + col;
        int chb = ch * 32 + icg * 8;
        u16x8 v = {0, 0, 0, 0, 0, 0, 0, 0};
        if ((unsigned)ih < 128u && (unsigned)ip < 128u && chb + 8 <= XR) {
          v = *reinterpret_cast<const u16x8*>(xtb + (size_t)(ih * 128 + ip) * XR + chb);
          if constexpr (AFFINE) {
            const float* ga = gA + b * 256 + chb;
            const float* gb2 = gB + b * 256 + chb;
            #pragma unroll
            for (int k = 0; k < 8; ++k)
              v[k] = f2bf(fmaxf(fmaf(bf2f(v[k]), ga[k], gb2[k]), 0.f));
          }
        }
        *reinterpret_cast<u16x8*>(&lb[(rc * 5 + icg) << 3]) = v;
      }
    }
    __syncthreads();
    #pragma unroll
    for (int kk = 0; kk < 9; ++kk) {
      const int kh = kk / 3, kw = kk - kh * 3;
      short8 afrag[NOF];
      const u16* wb = wt + ((size_t)kk * OC + oc0 + colA) * ICPAD + ch * 32 + g * 8;
      #pragma unroll
      for (int of = 0; of < NOF; ++of)
        afrag[of] = *reinterpret_cast<const short8*>(wb + (size_t)of * 16 * ICPAD);
      #pragma unroll
      for (int pf = 0; pf < 4; ++pf) {
        int colx = pf * 16 + colA + kw;
        short8 bfrag = *reinterpret_cast<const short8*>(
            &lb[((kh * 66 + colx) * 5 + g) << 3]);
        #pragma unroll
        for (int of = 0; of < NOF; ++of)
          acc[of][pf] = __builtin_amdgcn_mfma_f32_16x16x32_bf16(
              afrag[of], bfrag, acc[of][pf], 0, 0, 0);
      }
    }
  }
  #pragma unroll
  for (int of = 0; of < NOF; ++of) {
    float s = 0.f, ss = 0.f;
    #pragma unroll
    for (int pf = 0; pf < 4; ++pf) {
      int px = oh * 128 + ow0 + pf * 16 + colA;
      u16x4 o;
      #pragma unroll
      for (int r = 0; r < 4; ++r) {
        float v = acc[of][pf][r];
        if constexpr (RELU) v = fmaxf(v, 0.f);
        if constexpr (GNST) { s += v; ss = fmaf(v, v, ss); }
        o[r] = f2bf(v);
      }
      *reinterpret_cast<u16x4*>(
          outT + ((size_t)b * HW + px) * OROW + oc0 + of * 16 + g * 4) = o;
    }
    if constexpr (GNST) {
      #pragma unroll
      for (int off2 = 1; off2 < 16; off2 <<= 1) {
        s += __shfl_xor(s, off2);
        ss += __shfl_xor(ss, off2);
      }
      s += __shfl_xor(s, 16);
      ss += __shfl_xor(ss, 16);
      if (colA == 0 && (g & 1) == 0) {
        int grp = (oc0 + of * 16 + g * 4) >> 3;
        atomicAdd(gnsum + ((size_t)b * 32 + grp) * 2, s);
        atomicAdd(gnsum + ((size_t)b * 32 + grp) * 2 + 1, ss);
      }
    }
  }
}

// ---------------- GN finalize: sums -> per (b,c) affine a,b ----------------
__global__ __launch_bounds__(256) void gn_fin(
    const float* __restrict__ gnsum, const float* __restrict__ gg,
    const float* __restrict__ gb, float* __restrict__ gA,
    float* __restrict__ gB) {
  int b = blockIdx.x, c = threadIdx.x;
  int grp = c >> 3;
  float s = gnsum[((size_t)b * 32 + grp) * 2];
  float ss = gnsum[((size_t)b * 32 + grp) * 2 + 1];
  float m = s * (1.f / 131072.f);
  float var = ss * (1.f / 131072.f) - m * m;
  float istd = rsqrtf(var + 1e-5f);
  float a = istd * gg[c];
  gA[b * 256 + c] = a;
  gB[b * 256 + c] = gb[c] - m * a;
}

// ---------------- d3: 1x1 conv 64->1 on y2T [p][64] ----------------
__global__ __launch_bounds__(256) void d3_kernel(
    const u16* __restrict__ y2t, const float* __restrict__ w3,
    const float* __restrict__ b3, float* __restrict__ y3) {
  int idx = blockIdx.x * 256 + threadIdx.x;   // 8*16384
  const u16* r = y2t + (size_t)idx * 64;
  float acc = b3[0];
  #pragma unroll
  for (int cg = 0; cg < 8; ++cg) {
    u16x8 v = *reinterpret_cast<const u16x8*>(r + cg * 8);
    #pragma unroll
    for (int k = 0; k < 8; ++k) acc = fmaf(bf2f(v[k]), w3[cg * 8 + k], acc);
  }
  y3[idx] = acc;
}

// ---------------- bilinear upsample 128 -> 512 ----------------
__global__ __launch_bounds__(256) void upsample_kernel(
    const float* __restrict__ y3, float* __restrict__ out) {
  int idx = blockIdx.x * 256 + threadIdx.x;   // 8*512*512
  int b = idx >> 18;
  int rem = idx & 262143;
  int Y = rem >> 9, X = rem & 511;
  float sy = (Y + 0.5f) * 0.25f - 0.5f;
  float sx = (X + 0.5f) * 0.25f - 0.5f;
  float y0f = floorf(sy), x0f = floorf(sx);
  float fy = sy - y0f, fx = sx - x0f;
  int y0 = (int)y0f, x0 = (int)x0f;
  int y0c = max(y0, 0), y1c = min(y0 + 1, 127);
  int x0c = max(x0, 0), x1c = min(x0 + 1, 127);
  const float* yb = y3 + (size_t)b * HW;
  float v00 = yb[y0c * 128 + x0c], v01 = yb[y0c * 128 + x1c];
  float v10 = yb[y1c * 128 + x0c], v11 = yb[y1c * 128 + x1c];
  out[idx] = (1.f - fy) * ((1.f - fx) * v00 + fx * v01) +
             fy * ((1.f - fx) * v10 + fx * v11);
}

extern "C" void kernel_launch(void* const* d_in, const int* in_sizes, int n_in,
                              void* d_out, int out_size, void* d_ws, size_t ws_size,
                              hipStream_t stream) {
  const float* images  = (const float*)d_in[0];
  const int*   tokens  = (const int*)d_in[1];
  const float* tok512  = (const float*)d_in[2];
  const float* conv1_w = (const float*)d_in[3];
  const float* conv1_b = (const float*)d_in[4];
  const float* conv2_w = (const float*)d_in[5];
  const float* conv2_b = (const float*)d_in[6];
  const float* sp1_w   = (const float*)d_in[7];
  const float* sp1_b   = (const float*)d_in[8];
  const float* sp2_w   = (const float*)d_in[9];
  const float* sp2_b   = (const float*)d_in[10];
  const float* proj_w  = (const float*)d_in[11];
  const float* proj_b  = (const float*)d_in[12];
  const float* gate_w  = (const float*)d_in[13];
  const float* gate_b  = (const float*)d_in[14];
  const float* d1_w    = (const float*)d_in[15];
  const float* d1_b    = (const float*)d_in[16];
  const float* gn_g    = (const float*)d_in[17];
  const float* gn_b    = (const float*)d_in[18];
  const float* d2_w    = (const float*)d_in[19];
  const float* d2_b    = (const float*)d_in[20];
  const float* d3_w    = (const float*)d_in[21];
  const float* d3_b    = (const float*)d_in[22];

  float* outp = (float*)d_out;
  if (ws_size < WS_BYTES_NEEDED) {
    float v = 10000.0f + (float)(ws_size >> 20);
    fill_kernel<<<(out_size + 255) / 256, 256, 0, stream>>>(outp, out_size, v);
    return;
  }

  char* wsb = (char*)d_ws;
  u16*   xt    = (u16*)(wsb + OFF_XT);
  u16*   x1    = (u16*)(wsb + OFF_B);
  float* tokb  = (float*)(wsb + OFF_B);            // overlays x1 (dead)
  float* gvecb = (float*)(wsb + OFF_B + OFF_GVECB);
  u16*   y1t   = (u16*)(wsb + OFF_B);              // overlays tokb (dead)
  float* gnsum = (float*)(wsb + OFF_GNSUM);
  u16*   y2t   = (u16*)(wsb + OFF_Y2T);            // overlays XT (dead after d1)
  float* gA    = (float*)(wsb + OFF_GA);
  float* gB    = (float*)(wsb + OFF_GB);
  float* y3    = (float*)(wsb + OFF_Y3);

  u16* wt1 = (u16*)d_out;                          // d_out scratch until upsample
  u16* wt2 = (u16*)((char*)d_out + WT1_BYTES);

  prep_wt<<<(9 * 256 * 544 + 255) / 256, 256, 0, stream>>>(
      d1_w, wt1, 256, 513, 544, 9 * 256 * 544);
  prep_wt<<<(9 * 64 * 256 + 255) / 256, 256, 0, stream>>>(
      d2_w, wt2, 64, 256, 256, 9 * 64 * 256);
  zero_gnsum<<<1, 512, 0, stream>>>(gnsum);

  conv1_kernel<<<dim3(64, 32, 8), 256, 0, stream>>>(images, conv1_w, conv1_b, x1);
  conv2_kernel<<<dim3(16, 128, 8), 256, 0, stream>>>(
      x1, conv2_w, conv2_b, sp1_w, sp1_b, sp2_w, sp2_b, xt);
  token_kernel<<<BB * LL, 256, 0, stream>>>(tok512, proj_w, proj_b, gate_w,
                                            gate_b, tokb);
  gvec_kernel<<<BB, 256, 0, stream>>>(tokb, tokens, gvecb);
  attn_kernel<<<dim3(64, BB), 256, 0, stream>>>(xt, tokb, tokens, gvecb);
  // d1: 513->256 MFMA, fused GN stats, out y1T [p][256]
  convT_mfma<17, XROW, 256, 32, false, true, false, 256>
      <<<dim3(256, 2, 8), 256, 0, stream>>>(xt, wt1, d1_b, nullptr, nullptr,
                                            gnsum, y1t);
  gn_fin<<<8, 256, 0, stream>>>(gnsum, gn_g, gn_b, gA, gB);
  // d2: 256->64 MFMA, GN-affine+ReLU fused at staging, ReLU out, y2T [p][64]
  convT_mfma<8, 256, 64, 16, true, false, true, 64>
      <<<dim3(256, 1, 8), 256, 0, stream>>>(y1t, wt2, d2_b, gA, gB, nullptr, y2t);
  d3_kernel<<<512, 256, 0, stream>>>(y2t, d3_w, d3_b, y3);
  upsample_kernel<<<8192, 256, 0, stream>>>(y3, outp);
}

// Round 8
// 6937.777 us; speedup vs baseline: 1.0108x; 1.0108x over previous
//
#include <hip/hip_runtime.h>
#include <math.h>

typedef unsigned short u16;
typedef __attribute__((ext_vector_type(4))) unsigned short u16x4;
typedef __attribute__((ext_vector_type(8))) unsigned short u16x8;
typedef __attribute__((ext_vector_type(8))) short short8;   // MFMA A/B frag (8 bf16)
typedef __attribute__((ext_vector_type(4))) float f32x4;    // MFMA C/D frag

#define BB 8
#define CC 256
#define LL 77
#define HW 16384    // 128*128
#define XROW 520    // XT row stride in ch (513 padded to 8-multiple)

__device__ __forceinline__ float bf2f(u16 h) {
  return __uint_as_float(((unsigned)h) << 16);
}
__device__ __forceinline__ u16 f2bf(float f) {   // round-to-nearest-even
  unsigned u = __float_as_uint(f);
  unsigned r = (u + 0x7fffu + ((u >> 16) & 1u)) >> 16;
  return (u16)r;
}

// ---------------- workspace layout (BYTE offsets) ----------------
static const size_t OFF_XT    = 0;
static const size_t OFF_B     = 136314880;
static const size_t OFF_GVECB = 630784;          // relative to OFF_B
static const size_t OFF_PG    = 137363456;       // P [8][16384][96] bf16 (25.2MB)
static const size_t OFF_GNSUM = 203423744;
static const size_t WS_BYTES_NEEDED = 203425792;  // ~194.0 MiB
// Region-A reuse offsets (absolute):
static const size_t OFF_Y2T = 0;
static const size_t OFF_GA  = 16777216;
static const size_t OFF_GB  = 16785408;
static const size_t OFF_Y3  = 16793600;
// d_out scratch: wt1 then wt2 (dead until final upsample)
static const size_t WT1_BYTES = 9u * 256u * 544u * 2u;   // 2,506,752 (16B aligned)

// ---------------- diagnostic fill (only if ws too small) ----------------
__global__ __launch_bounds__(256) void fill_kernel(float* __restrict__ out,
                                                   int n, float v) {
  int i = blockIdx.x * 256 + threadIdx.x;
  if (i < n) out[i] = v;
}

__global__ __launch_bounds__(512) void zero_gnsum(float* __restrict__ g) {
  g[threadIdx.x] = 0.f;
}

// ---------------- weight transpose: w[oc][ic][3][3] f32 -> wt[kk][oc][icpad] bf16
__global__ __launch_bounds__(256) void prep_wt(
    const float* __restrict__ w, u16* __restrict__ wt,
    int OC, int ICSRC, int ICPAD, int total) {
  int idx = blockIdx.x * 256 + threadIdx.x;
  if (idx >= total) return;
  int ic = idx % ICPAD;
  int oc = (idx / ICPAD) % OC;
  int kk = idx / (ICPAD * OC);
  float v = 0.f;
  if (ic < ICSRC) v = w[((size_t)oc * ICSRC + ic) * 9 + kk];
  wt[idx] = f2bf(v);
}

// ---------------- conv1: 3->64, stride 2, 512->256, relu (f32 in, bf16 [c][p] out)
__global__ __launch_bounds__(256) void conv1_kernel(
    const float* __restrict__ in, const float* __restrict__ w,
    const float* __restrict__ bias, u16* __restrict__ out) {
  constexpr int IC = 3, WIN = 512, WOUT = 256, OC = 64;
  constexpr int TPR = WOUT / 4;
  __shared__ float wl[IC * 9 * 2];
  const int tid = threadIdx.x;
  const int oc0 = blockIdx.y * 2;
  const int b = blockIdx.z;
  for (int i = tid; i < IC * 9 * 2; i += 256) {
    int j = (i >= IC * 9) ? 1 : 0;
    int t = i - j * IC * 9;
    wl[t * 2 + j] = w[(size_t)(oc0 + j) * IC * 9 + t];
  }
  __syncthreads();
  const int t = tid % TPR;
  const int oh = blockIdx.x * (256 / TPR) + tid / TPR;
  const int ow0 = t * 4;
  float acc[2][4];
  #pragma unroll
  for (int j = 0; j < 2; ++j) {
    float bb = bias[oc0 + j];
    #pragma unroll
    for (int i = 0; i < 4; ++i) acc[j][i] = bb;
  }
  for (int ic = 0; ic < IC; ++ic) {
    const float* plane = in + ((size_t)b * IC + ic) * ((size_t)WIN * WIN);
    #pragma unroll
    for (int kh = 0; kh < 3; ++kh) {
      int ih = 2 * oh + kh - 1;
      if ((unsigned)ih >= (unsigned)WIN) continue;
      const float* row = plane + (size_t)ih * WIN;
      const int base = ow0 * 2;
      float v[9];
      float4 a = *reinterpret_cast<const float4*>(row + base);
      float4 c4 = *reinterpret_cast<const float4*>(row + base + 4);
      v[1] = a.x; v[2] = a.y; v[3] = a.z; v[4] = a.w;
      v[5] = c4.x; v[6] = c4.y; v[7] = c4.z; v[8] = c4.w;
      v[0] = (base > 0) ? row[base - 1] : 0.f;
      const float2* wp = reinterpret_cast<const float2*>(wl) + (ic * 3 + kh) * 3;
      float2 w0 = wp[0], w1 = wp[1], w2 = wp[2];
      #pragma unroll
      for (int i = 0; i < 4; ++i) {
        acc[0][i] += v[2 * i] * w0.x + v[2 * i + 1] * w1.x + v[2 * i + 2] * w2.x;
        acc[1][i] += v[2 * i] * w0.y + v[2 * i + 1] * w1.y + v[2 * i + 2] * w2.y;
      }
    }
  }
  const int p = oh * WOUT + ow0;
  #pragma unroll
  for (int j = 0; j < 2; ++j) {
    u16x4 o;
    #pragma unroll
    for (int i = 0; i < 4; ++i) o[i] = f2bf(fmaxf(acc[j][i], 0.f));
    *reinterpret_cast<u16x4*>(out + ((size_t)b * OC + oc0 + j) * (WOUT * WOUT) + p) = o;
  }
}

// ---------------- conv2: 64->256, stride 2, relu, + inline pos; writes XT[p][oc]
__global__ __launch_bounds__(256) void conv2_kernel(
    const u16* __restrict__ x1, const float* __restrict__ w,
    const float* __restrict__ bias,
    const float* __restrict__ sp1_w, const float* __restrict__ sp1_b,
    const float* __restrict__ sp2_w, const float* __restrict__ sp2_b,
    u16* __restrict__ xt) {
  constexpr int IC = 64, WIN = 256;
  __shared__ float wl[IC * 9 * 2];
  __shared__ float s1w[128], s1b[64], s2w[128];
  const int tid = threadIdx.x;
  const int oc0 = blockIdx.y * 2;
  const int b = blockIdx.z;
  for (int i = tid; i < IC * 9 * 2; i += 256) {
    int j = (i >= IC * 9) ? 1 : 0;
    int t = i - j * IC * 9;
    wl[t * 2 + j] = w[(size_t)(oc0 + j) * IC * 9 + t];
  }
  if (tid < 128) s1w[tid] = sp1_w[tid];
  if (tid < 64) s1b[tid] = sp1_b[tid];
  if (tid < 128) s2w[tid] = sp2_w[(size_t)(oc0 + (tid >> 6)) * 64 + (tid & 63)];
  __syncthreads();
  const int t = tid & 31;
  const int oh = blockIdx.x * 8 + (tid >> 5);
  const int ow0 = t * 4;
  float acc[2][4];
  #pragma unroll
  for (int j = 0; j < 2; ++j) {
    float bb = bias[oc0 + j];
    #pragma unroll
    for (int i = 0; i < 4; ++i) acc[j][i] = bb;
  }
  for (int ic = 0; ic < IC; ++ic) {
    const u16* plane = x1 + ((size_t)b * IC + ic) * ((size_t)WIN * WIN);
    #pragma unroll
    for (int kh = 0; kh < 3; ++kh) {
      int ih = 2 * oh + kh - 1;
      if ((unsigned)ih >= (unsigned)WIN) continue;
      const u16* row = plane + (size_t)ih * WIN;
      const int base = ow0 * 2;
      float v[9];
      u16x8 a = *reinterpret_cast<const u16x8*>(row + base);
      #pragma unroll
      for (int i2 = 0; i2 < 8; ++i2) v[1 + i2] = bf2f(a[i2]);
      v[0] = (base > 0) ? bf2f(row[base - 1]) : 0.f;
      const float2* wp = reinterpret_cast<const float2*>(wl) + (ic * 3 + kh) * 3;
      float2 w0 = wp[0], w1 = wp[1], w2 = wp[2];
      #pragma unroll
      for (int i = 0; i < 4; ++i) {
        acc[0][i] += v[2 * i] * w0.x + v[2 * i + 1] * w1.x + v[2 * i + 2] * w2.x;
        acc[1][i] += v[2 * i] * w0.y + v[2 * i + 1] * w1.y + v[2 * i + 2] * w2.y;
      }
    }
  }
  // epilogue: relu(conv) + pos(oc, px), scatter into XT[p][oc0..oc0+1]
  const float yy = -1.f + oh * (2.f / 127.f);
  const float sb0 = sp2_b[oc0], sb1 = sp2_b[oc0 + 1];
  u16* xb = xt + (size_t)b * HW * XROW;
  #pragma unroll
  for (int i = 0; i < 4; ++i) {
    float xxv = -1.f + (ow0 + i) * (2.f / 127.f);
    float pa = sb0, pb = sb1;
    #pragma unroll 8
    for (int h = 0; h < 64; ++h) {
      float hid = fmaxf(s1w[2 * h] * xxv + s1w[2 * h + 1] * yy + s1b[h], 0.f);
      pa = fmaf(s2w[h], hid, pa);
      pb = fmaf(s2w[64 + h], hid, pb);
    }
    float r0 = fmaxf(acc[0][i], 0.f) + pa;
    float r1 = fmaxf(acc[1][i], 0.f) + pb;
    int p = oh * 128 + ow0 + i;
    unsigned pk = (unsigned)f2bf(r0) | ((unsigned)f2bf(r1) << 16);
    *reinterpret_cast<unsigned*>(xb + (size_t)p * XROW + oc0) = pk;
  }
}

// ---------------- token pipeline: proj -> gate -> l2norm (f32 out) ----------
__global__ __launch_bounds__(256) void token_kernel(
    const float* __restrict__ tok512, const float* __restrict__ proj_w,
    const float* __restrict__ proj_b, const float* __restrict__ gate_w,
    const float* __restrict__ gate_b, float* __restrict__ tok_out) {
  __shared__ float t512[512];
  __shared__ float prj[256];
  __shared__ float red[4];
  int bl = blockIdx.x;
  int c = threadIdx.x;
  const float* trow = tok512 + (size_t)bl * 512;
  t512[c] = trow[c];
  t512[c + 256] = trow[c + 256];
  __syncthreads();
  float acc = proj_b[c];
  #pragma unroll 4
  for (int k = 0; k < 512; ++k) acc = fmaf(t512[k], proj_w[k * 256 + c], acc);
  prj[c] = acc;
  __syncthreads();
  float acc2 = gate_b[c];
  #pragma unroll 4
  for (int k = 0; k < 256; ++k) acc2 = fmaf(prj[k], gate_w[k * 256 + c], acc2);
  float g = 1.f / (1.f + __expf(-acc2));
  float tv = g * acc;
  float ss = tv * tv;
  #pragma unroll
  for (int off = 1; off < 64; off <<= 1) ss += __shfl_xor(ss, off);
  if ((c & 63) == 0) red[c >> 6] = ss;
  __syncthreads();
  float tot = red[0] + red[1] + red[2] + red[3];
  tok_out[(size_t)bl * 256 + c] = tv * (1.f / fmaxf(sqrtf(tot), 1e-12f));
}

// ---------------- gvec ----------------
__global__ __launch_bounds__(256) void gvec_kernel(
    const float* __restrict__ tok, const int* __restrict__ tokens,
    float* __restrict__ gvec) {
  __shared__ float red[4];
  int b = blockIdx.x, c = threadIdx.x;
  float s = 0.f;
  for (int l = 0; l < LL; ++l) {
    if (tokens[b * LL + l] != 0) s += tok[((size_t)b * LL + l) * 256 + c];
  }
  float ss = s * s;
  #pragma unroll
  for (int off = 1; off < 64; off <<= 1) ss += __shfl_xor(ss, off);
  if ((c & 63) == 0) red[c >> 6] = ss;
  __syncthreads();
  float tot = red[0] + red[1] + red[2] + red[3];
  gvec[b * 256 + c] = s * (1.f / fmaxf(sqrtf(tot), 1e-12f));
}

// ---------------- attn pass 1: scores + softmax -> P (global), sim -> XT ----
// one thread per px; s[77] + x[32] live (~130 VGPR, no spill).
// P row = 96 bf16 = 192B = exactly 3 aligned 64B lines per thread.
__global__ __launch_bounds__(256, 1) void attn_score(
    u16* __restrict__ xt, const float* __restrict__ tok,
    const int* __restrict__ tokens, const float* __restrict__ gvec,
    u16* __restrict__ pg) {
  __shared__ u16 ltok[LL * 256];   // bf16 tokens (39.4 KB)
  __shared__ float lgv[256];
  __shared__ u16 lval[LL + 3];
  const int tid = threadIdx.x;
  const int b = blockIdx.y;
  for (int slot = tid; slot < LL * 32; slot += 256) {
    int l = slot >> 5, cg = slot & 31;
    const float* tp = tok + ((size_t)b * LL + l) * 256 + cg * 8;
    float4 t0 = *reinterpret_cast<const float4*>(tp);
    float4 t1 = *reinterpret_cast<const float4*>(tp + 4);
    u16x8 v = {f2bf(t0.x), f2bf(t0.y), f2bf(t0.z), f2bf(t0.w),
               f2bf(t1.x), f2bf(t1.y), f2bf(t1.z), f2bf(t1.w)};
    *reinterpret_cast<u16x8*>(&ltok[l * 256 + cg * 8]) = v;
  }
  if (tid < LL) lval[tid] = (tokens[b * LL + tid] != 0) ? 1 : 0;
  lgv[tid] = gvec[b * 256 + tid];
  __syncthreads();
  const int p = blockIdx.x * 256 + tid;
  const u16* xr = xt + ((size_t)b * HW + p) * XROW;
  float s[LL];
  #pragma unroll
  for (int l = 0; l < LL; ++l) s[l] = 0.f;
  float ssum = 0.f, simacc = 0.f;
  #pragma unroll 1
  for (int c0 = 0; c0 < 256; c0 += 32) {
    float x[32];
    #pragma unroll
    for (int q = 0; q < 4; ++q) {          // 4 consecutive 16B loads = 64B
      u16x8 iv = *reinterpret_cast<const u16x8*>(xr + c0 + q * 8);
      #pragma unroll
      for (int k = 0; k < 8; ++k) x[q * 8 + k] = bf2f(iv[k]);
    }
    #pragma unroll
    for (int k = 0; k < 32; ++k) {
      ssum = fmaf(x[k], x[k], ssum);
      simacc = fmaf(x[k], lgv[c0 + k], simacc);
    }
    #pragma unroll
    for (int l = 0; l < LL; ++l) {
      const u16* tr = &ltok[l * 256 + c0];
      float a2 = s[l];
      #pragma unroll
      for (int q = 0; q < 4; ++q) {
        u16x8 tv = *reinterpret_cast<const u16x8*>(tr + q * 8);
        #pragma unroll
        for (int k = 0; k < 8; ++k) a2 = fmaf(x[q * 8 + k], bf2f(tv[k]), a2);
      }
      s[l] = a2;
    }
  }
  float invn = 1.f / fmaxf(sqrtf(ssum), 1e-12f);
  float sc = invn * 0.0625f;
  float m = -1e30f;
  #pragma unroll
  for (int l = 0; l < LL; ++l) {
    s[l] = lval[l] ? s[l] * sc : -10000.f;
    m = fmaxf(m, s[l]);
  }
  float sum = 0.f;
  #pragma unroll
  for (int l = 0; l < LL; ++l) {
    s[l] = __expf(s[l] - m);
    sum += s[l];
  }
  const float rs = 1.f / sum;
  // write P row (77 weights, zero pad to 96)
  u16* pr = pg + ((size_t)b * HW + p) * 96;
  #pragma unroll
  for (int q = 0; q < 12; ++q) {
    u16x8 ov;
    #pragma unroll
    for (int k = 0; k < 8; ++k) {
      int l = q * 8 + k;
      ov[k] = (l < LL) ? f2bf(s[l] * rs) : (u16)0;
    }
    *reinterpret_cast<u16x8*>(pr + q * 8) = ov;
  }
  u16x8 sv = {f2bf(simacc * invn), 0, 0, 0, 0, 0, 0, 0};
  *reinterpret_cast<u16x8*>(xt + ((size_t)b * HW + p) * XROW + 512) = sv;
}

// ---------------- attn pass 2: ctx = P @ tok -> XT ctx channels ----------
// P row kept PACKED in 10 u16x8 (40 VGPRs); a[32] per chunk (~90 VGPR total).
__global__ __launch_bounds__(256, 1) void attn_ctx(
    u16* __restrict__ xt, const float* __restrict__ tok,
    const u16* __restrict__ pg) {
  __shared__ u16 ltok[LL * 256];   // bf16 tokens (39.4 KB)
  const int tid = threadIdx.x;
  const int b = blockIdx.y;
  for (int slot = tid; slot < LL * 32; slot += 256) {
    int l = slot >> 5, cg = slot & 31;
    const float* tp = tok + ((size_t)b * LL + l) * 256 + cg * 8;
    float4 t0 = *reinterpret_cast<const float4*>(tp);
    float4 t1 = *reinterpret_cast<const float4*>(tp + 4);
    u16x8 v = {f2bf(t0.x), f2bf(t0.y), f2bf(t0.z), f2bf(t0.w),
               f2bf(t1.x), f2bf(t1.y), f2bf(t1.z), f2bf(t1.w)};
    *reinterpret_cast<u16x8*>(&ltok[l * 256 + cg * 8]) = v;
  }
  __syncthreads();
  const int p = blockIdx.x * 256 + tid;
  const u16* pr = pg + ((size_t)b * HW + p) * 96;
  u16x8 pw[10];   // 80 >= 77 weights, packed bf16
  #pragma unroll
  for (int q = 0; q < 10; ++q)
    pw[q] = *reinterpret_cast<const u16x8*>(pr + q * 8);
  u16* xw = xt + ((size_t)b * HW + p) * XROW + 256;
  #pragma unroll 1
  for (int c0 = 0; c0 < 256; c0 += 32) {
    float a[32];
    #pragma unroll
    for (int k = 0; k < 32; ++k) a[k] = 0.f;
    #pragma unroll
    for (int l = 0; l < LL; ++l) {
      float sl = bf2f(pw[l >> 3][l & 7]);
      const u16* tr = &ltok[l * 256 + c0];
      #pragma unroll
      for (int q = 0; q < 4; ++q) {
        u16x8 tv = *reinterpret_cast<const u16x8*>(tr + q * 8);
        #pragma unroll
        for (int k = 0; k < 8; ++k) a[q * 8 + k] = fmaf(sl, bf2f(tv[k]), a[q * 8 + k]);
      }
    }
    #pragma unroll
    for (int q = 0; q < 4; ++q) {
      u16x8 ov;
      #pragma unroll
      for (int k = 0; k < 8; ++k) ov[k] = f2bf(a[q * 8 + k]);
      *reinterpret_cast<u16x8*>(xw + c0 + q * 8) = ov;
    }
  }
}

// ---------------- MFMA conv 3x3 stride-1 on transposed input ----------------
template <int CHUNKS, int XR, int OC, int OCW, bool AFFINE, bool GNST, bool RELU,
          int OROW>
__global__ __launch_bounds__(256) void convT_mfma(
    const u16* __restrict__ xt, const u16* __restrict__ wt,
    const float* __restrict__ bias, const float* __restrict__ gA,
    const float* __restrict__ gB, float* __restrict__ gnsum,
    u16* __restrict__ outT) {
  constexpr int ICPAD = CHUNKS * 32;
  constexpr int OCB = 4 * OCW;
  constexpr int NOF = OCW / 16;
  __shared__ u16 lb[7920];   // 3*66*5 slots * 8 u16 = 15,840 B
  const int tid = threadIdx.x;
  const int lane = tid & 63;
  const int w = tid >> 6;
  const int oh = blockIdx.x >> 1;
  const int ow0 = (blockIdx.x & 1) << 6;
  const int oc0 = blockIdx.y * OCB + w * OCW;
  const int b = blockIdx.z;
  const int colA = lane & 15;
  const int g = lane >> 4;

  f32x4 acc[NOF][4];
  #pragma unroll
  for (int of = 0; of < NOF; ++of) {
    f32x4 bv;
    #pragma unroll
    for (int r = 0; r < 4; ++r) bv[r] = bias[oc0 + of * 16 + g * 4 + r];
    #pragma unroll
    for (int pf = 0; pf < 4; ++pf) acc[of][pf] = bv;
  }

  const u16* xtb = xt + (size_t)b * HW * XR;
  for (int ch = 0; ch < CHUNKS; ++ch) {
    __syncthreads();
    #pragma unroll
    for (int it = 0; it < 4; ++it) {
      int slot = it * 256 + tid;
      if (slot < 792) {
        int icg = slot & 3;
        int rc = slot >> 2;
        int col = rc % 66;
        int row = rc / 66;
        int ih = oh + row - 1;
        int ip = ow0 - 1 + col;
        int chb = ch * 32 + icg * 8;
        u16x8 v = {0, 0, 0, 0, 0, 0, 0, 0};
        if ((unsigned)ih < 128u && (unsigned)ip < 128u && chb + 8 <= XR) {
          v = *reinterpret_cast<const u16x8*>(xtb + (size_t)(ih * 128 + ip) * XR + chb);
          if constexpr (AFFINE) {
            const float* ga = gA + b * 256 + chb;
            const float* gb2 = gB + b * 256 + chb;
            #pragma unroll
            for (int k = 0; k < 8; ++k)
              v[k] = f2bf(fmaxf(fmaf(bf2f(v[k]), ga[k], gb2[k]), 0.f));
          }
        }
        *reinterpret_cast<u16x8*>(&lb[(rc * 5 + icg) << 3]) = v;
      }
    }
    __syncthreads();
    #pragma unroll
    for (int kk = 0; kk < 9; ++kk) {
      const int kh = kk / 3, kw = kk - kh * 3;
      short8 afrag[NOF];
      const u16* wb = wt + ((size_t)kk * OC + oc0 + colA) * ICPAD + ch * 32 + g * 8;
      #pragma unroll
      for (int of = 0; of < NOF; ++of)
        afrag[of] = *reinterpret_cast<const short8*>(wb + (size_t)of * 16 * ICPAD);
      #pragma unroll
      for (int pf = 0; pf < 4; ++pf) {
        int colx = pf * 16 + colA + kw;
        short8 bfrag = *reinterpret_cast<const short8*>(
            &lb[((kh * 66 + colx) * 5 + g) << 3]);
        #pragma unroll
        for (int of = 0; of < NOF; ++of)
          acc[of][pf] = __builtin_amdgcn_mfma_f32_16x16x32_bf16(
              afrag[of], bfrag, acc[of][pf], 0, 0, 0);
      }
    }
  }
  #pragma unroll
  for (int of = 0; of < NOF; ++of) {
    float s = 0.f, ss = 0.f;
    #pragma unroll
    for (int pf = 0; pf < 4; ++pf) {
      int px = oh * 128 + ow0 + pf * 16 + colA;
      u16x4 o;
      #pragma unroll
      for (int r = 0; r < 4; ++r) {
        float v = acc[of][pf][r];
        if constexpr (RELU) v = fmaxf(v, 0.f);
        if constexpr (GNST) { s += v; ss = fmaf(v, v, ss); }
        o[r] = f2bf(v);
      }
      *reinterpret_cast<u16x4*>(
          outT + ((size_t)b * HW + px) * OROW + oc0 + of * 16 + g * 4) = o;
    }
    if constexpr (GNST) {
      #pragma unroll
      for (int off2 = 1; off2 < 16; off2 <<= 1) {
        s += __shfl_xor(s, off2);
        ss += __shfl_xor(ss, off2);
      }
      s += __shfl_xor(s, 16);
      ss += __shfl_xor(ss, 16);
      if (colA == 0 && (g & 1) == 0) {
        int grp = (oc0 + of * 16 + g * 4) >> 3;
        atomicAdd(gnsum + ((size_t)b * 32 + grp) * 2, s);
        atomicAdd(gnsum + ((size_t)b * 32 + grp) * 2 + 1, ss);
      }
    }
  }
}

// ---------------- GN finalize: sums -> per (b,c) affine a,b ----------------
__global__ __launch_bounds__(256) void gn_fin(
    const float* __restrict__ gnsum, const float* __restrict__ gg,
    const float* __restrict__ gb, float* __restrict__ gA,
    float* __restrict__ gB) {
  int b = blockIdx.x, c = threadIdx.x;
  int grp = c >> 3;
  float s = gnsum[((size_t)b * 32 + grp) * 2];
  float ss = gnsum[((size_t)b * 32 + grp) * 2 + 1];
  float m = s * (1.f / 131072.f);
  float var = ss * (1.f / 131072.f) - m * m;
  float istd = rsqrtf(var + 1e-5f);
  float a = istd * gg[c];
  gA[b * 256 + c] = a;
  gB[b * 256 + c] = gb[c] - m * a;
}

// ---------------- d3: 1x1 conv 64->1 on y2T [p][64] ----------------
__global__ __launch_bounds__(256) void d3_kernel(
    const u16* __restrict__ y2t, const float* __restrict__ w3,
    const float* __restrict__ b3, float* __restrict__ y3) {
  int idx = blockIdx.x * 256 + threadIdx.x;   // 8*16384
  const u16* r = y2t + (size_t)idx * 64;
  float acc = b3[0];
  #pragma unroll
  for (int cg = 0; cg < 8; ++cg) {
    u16x8 v = *reinterpret_cast<const u16x8*>(r + cg * 8);
    #pragma unroll
    for (int k = 0; k < 8; ++k) acc = fmaf(bf2f(v[k]), w3[cg * 8 + k], acc);
  }
  y3[idx] = acc;
}

// ---------------- bilinear upsample 128 -> 512 ----------------
__global__ __launch_bounds__(256) void upsample_kernel(
    const float* __restrict__ y3, float* __restrict__ out) {
  int idx = blockIdx.x * 256 + threadIdx.x;   // 8*512*512
  int b = idx >> 18;
  int rem = idx & 262143;
  int Y = rem >> 9, X = rem & 511;
  float sy = (Y + 0.5f) * 0.25f - 0.5f;
  float sx = (X + 0.5f) * 0.25f - 0.5f;
  float y0f = floorf(sy), x0f = floorf(sx);
  float fy = sy - y0f, fx = sx - x0f;
  int y0 = (int)y0f, x0 = (int)x0f;
  int y0c = max(y0, 0), y1c = min(y0 + 1, 127);
  int x0c = max(x0, 0), x1c = min(x0 + 1, 127);
  const float* yb = y3 + (size_t)b * HW;
  float v00 = yb[y0c * 128 + x0c], v01 = yb[y0c * 128 + x1c];
  float v10 = yb[y1c * 128 + x0c], v11 = yb[y1c * 128 + x1c];
  out[idx] = (1.f - fy) * ((1.f - fx) * v00 + fx * v01) +
             fy * ((1.f - fx) * v10 + fx * v11);
}

extern "C" void kernel_launch(void* const* d_in, const int* in_sizes, int n_in,
                              void* d_out, int out_size, void* d_ws, size_t ws_size,
                              hipStream_t stream) {
  const float* images  = (const float*)d_in[0];
  const int*   tokens  = (const int*)d_in[1];
  const float* tok512  = (const float*)d_in[2];
  const float* conv1_w = (const float*)d_in[3];
  const float* conv1_b = (const float*)d_in[4];
  const float* conv2_w = (const float*)d_in[5];
  const float* conv2_b = (const float*)d_in[6];
  const float* sp1_w   = (const float*)d_in[7];
  const float* sp1_b   = (const float*)d_in[8];
  const float* sp2_w   = (const float*)d_in[9];
  const float* sp2_b   = (const float*)d_in[10];
  const float* proj_w  = (const float*)d_in[11];
  const float* proj_b  = (const float*)d_in[12];
  const float* gate_w  = (const float*)d_in[13];
  const float* gate_b  = (const float*)d_in[14];
  const float* d1_w    = (const float*)d_in[15];
  const float* d1_b    = (const float*)d_in[16];
  const float* gn_g    = (const float*)d_in[17];
  const float* gn_b    = (const float*)d_in[18];
  const float* d2_w    = (const float*)d_in[19];
  const float* d2_b    = (const float*)d_in[20];
  const float* d3_w    = (const float*)d_in[21];
  const float* d3_b    = (const float*)d_in[22];

  float* outp = (float*)d_out;
  if (ws_size < WS_BYTES_NEEDED) {
    float v = 10000.0f + (float)(ws_size >> 20);
    fill_kernel<<<(out_size + 255) / 256, 256, 0, stream>>>(outp, out_size, v);
    return;
  }

  char* wsb = (char*)d_ws;
  u16*   xt    = (u16*)(wsb + OFF_XT);
  u16*   x1    = (u16*)(wsb + OFF_B);
  float* tokb  = (float*)(wsb + OFF_B);            // overlays x1 (dead)
  float* gvecb = (float*)(wsb + OFF_B + OFF_GVECB);
  u16*   pgb   = (u16*)(wsb + OFF_PG);             // P scratch (dead before y1t)
  u16*   y1t   = (u16*)(wsb + OFF_B);              // overlays tokb/P (dead)
  float* gnsum = (float*)(wsb + OFF_GNSUM);
  u16*   y2t   = (u16*)(wsb + OFF_Y2T);            // overlays XT (dead after d1)
  float* gA    = (float*)(wsb + OFF_GA);
  float* gB    = (float*)(wsb + OFF_GB);
  float* y3    = (float*)(wsb + OFF_Y3);

  u16* wt1 = (u16*)d_out;                          // d_out scratch until upsample
  u16* wt2 = (u16*)((char*)d_out + WT1_BYTES);

  prep_wt<<<(9 * 256 * 544 + 255) / 256, 256, 0, stream>>>(
      d1_w, wt1, 256, 513, 544, 9 * 256 * 544);
  prep_wt<<<(9 * 64 * 256 + 255) / 256, 256, 0, stream>>>(
      d2_w, wt2, 64, 256, 256, 9 * 64 * 256);
  zero_gnsum<<<1, 512, 0, stream>>>(gnsum);

  conv1_kernel<<<dim3(64, 32, 8), 256, 0, stream>>>(images, conv1_w, conv1_b, x1);
  conv2_kernel<<<dim3(16, 128, 8), 256, 0, stream>>>(
      x1, conv2_w, conv2_b, sp1_w, sp1_b, sp2_w, sp2_b, xt);
  token_kernel<<<BB * LL, 256, 0, stream>>>(tok512, proj_w, proj_b, gate_w,
                                            gate_b, tokb);
  gvec_kernel<<<BB, 256, 0, stream>>>(tokb, tokens, gvecb);
  attn_score<<<dim3(64, BB), 256, 0, stream>>>(xt, tokb, tokens, gvecb, pgb);
  attn_ctx<<<dim3(64, BB), 256, 0, stream>>>(xt, tokb, pgb);
  // d1: 513->256 MFMA, fused GN stats, out y1T [p][256]
  convT_mfma<17, XROW, 256, 32, false, true, false, 256>
      <<<dim3(256, 2, 8), 256, 0, stream>>>(xt, wt1, d1_b, nullptr, nullptr,
                                            gnsum, y1t);
  gn_fin<<<8, 256, 0, stream>>>(gnsum, gn_g, gn_b, gA, gB);
  // d2: 256->64 MFMA, GN-affine+ReLU fused at staging, ReLU out, y2T [p][64]
  convT_mfma<8, 256, 64, 16, true, false, true, 64>
      <<<dim3(256, 1, 8), 256, 0, stream>>>(y1t, wt2, d2_b, gA, gB, nullptr, y2t);
  d3_kernel<<<512, 256, 0, stream>>>(y2t, d3_w, d3_b, y3);
  upsample_kernel<<<8192, 256, 0, stream>>>(y3, outp);
}

// Round 9
// 2352.898 us; speedup vs baseline: 2.9804x; 2.9486x over previous
//
#include <hip/hip_runtime.h>
#include <math.h>

typedef unsigned short u16;
typedef __attribute__((ext_vector_type(4))) unsigned short u16x4;
typedef __attribute__((ext_vector_type(8))) unsigned short u16x8;
typedef __attribute__((ext_vector_type(8))) short short8;   // MFMA A/B frag (8 bf16)
typedef __attribute__((ext_vector_type(4))) float f32x4;    // MFMA C/D frag

#define BB 8
#define CC 256
#define LL 77
#define HW 16384    // 128*128
#define XROW 520    // XT row stride in ch (513 padded to 8-multiple)

__device__ __forceinline__ float bf2f(u16 h) {
  return __uint_as_float(((unsigned)h) << 16);
}
__device__ __forceinline__ u16 f2bf(float f) {   // round-to-nearest-even
  unsigned u = __float_as_uint(f);
  unsigned r = (u + 0x7fffu + ((u >> 16) & 1u)) >> 16;
  return (u16)r;
}

// ---------------- workspace layout (BYTE offsets) ----------------
static const size_t OFF_XT    = 0;
static const size_t OFF_B     = 136314880;
static const size_t OFF_GVECB = 630784;          // relative to OFF_B
static const size_t OFF_PG    = 137363456;       // P [8][16384][96] bf16 (25.2MB)
static const size_t OFF_GNSUM = 203423744;
static const size_t WS_BYTES_NEEDED = 203425792;  // ~194.0 MiB
// Region-A reuse offsets (absolute):
static const size_t OFF_Y2T = 0;
static const size_t OFF_GA  = 16777216;
static const size_t OFF_GB  = 16785408;
static const size_t OFF_Y3  = 16793600;
// d_out scratch: wt1 then wt2 (dead until final upsample)
static const size_t WT1_BYTES = 9u * 256u * 544u * 2u;   // 2,506,752 (16B aligned)

// ---------------- diagnostic fill (only if ws too small) ----------------
__global__ __launch_bounds__(256) void fill_kernel(float* __restrict__ out,
                                                   int n, float v) {
  int i = blockIdx.x * 256 + threadIdx.x;
  if (i < n) out[i] = v;
}

__global__ __launch_bounds__(512) void zero_gnsum(float* __restrict__ g) {
  g[threadIdx.x] = 0.f;
}

// ---------------- weight transpose: w[oc][ic][3][3] f32 -> wt[kk][oc][icpad] bf16
__global__ __launch_bounds__(256) void prep_wt(
    const float* __restrict__ w, u16* __restrict__ wt,
    int OC, int ICSRC, int ICPAD, int total) {
  int idx = blockIdx.x * 256 + threadIdx.x;
  if (idx >= total) return;
  int ic = idx % ICPAD;
  int oc = (idx / ICPAD) % OC;
  int kk = idx / (ICPAD * OC);
  float v = 0.f;
  if (ic < ICSRC) v = w[((size_t)oc * ICSRC + ic) * 9 + kk];
  wt[idx] = f2bf(v);
}

// ---------------- conv1: 3->64, stride 2, 512->256, relu (f32 in, bf16 [c][p] out)
__global__ __launch_bounds__(256) void conv1_kernel(
    const float* __restrict__ in, const float* __restrict__ w,
    const float* __restrict__ bias, u16* __restrict__ out) {
  constexpr int IC = 3, WIN = 512, WOUT = 256, OC = 64;
  constexpr int TPR = WOUT / 4;
  __shared__ float wl[IC * 9 * 2];
  const int tid = threadIdx.x;
  const int oc0 = blockIdx.y * 2;
  const int b = blockIdx.z;
  for (int i = tid; i < IC * 9 * 2; i += 256) {
    int j = (i >= IC * 9) ? 1 : 0;
    int t = i - j * IC * 9;
    wl[t * 2 + j] = w[(size_t)(oc0 + j) * IC * 9 + t];
  }
  __syncthreads();
  const int t = tid % TPR;
  const int oh = blockIdx.x * (256 / TPR) + tid / TPR;
  const int ow0 = t * 4;
  float acc[2][4];
  #pragma unroll
  for (int j = 0; j < 2; ++j) {
    float bb = bias[oc0 + j];
    #pragma unroll
    for (int i = 0; i < 4; ++i) acc[j][i] = bb;
  }
  for (int ic = 0; ic < IC; ++ic) {
    const float* plane = in + ((size_t)b * IC + ic) * ((size_t)WIN * WIN);
    #pragma unroll
    for (int kh = 0; kh < 3; ++kh) {
      int ih = 2 * oh + kh - 1;
      if ((unsigned)ih >= (unsigned)WIN) continue;
      const float* row = plane + (size_t)ih * WIN;
      const int base = ow0 * 2;
      float v[9];
      float4 a = *reinterpret_cast<const float4*>(row + base);
      float4 c4 = *reinterpret_cast<const float4*>(row + base + 4);
      v[1] = a.x; v[2] = a.y; v[3] = a.z; v[4] = a.w;
      v[5] = c4.x; v[6] = c4.y; v[7] = c4.z; v[8] = c4.w;
      v[0] = (base > 0) ? row[base - 1] : 0.f;
      const float2* wp = reinterpret_cast<const float2*>(wl) + (ic * 3 + kh) * 3;
      float2 w0 = wp[0], w1 = wp[1], w2 = wp[2];
      #pragma unroll
      for (int i = 0; i < 4; ++i) {
        acc[0][i] += v[2 * i] * w0.x + v[2 * i + 1] * w1.x + v[2 * i + 2] * w2.x;
        acc[1][i] += v[2 * i] * w0.y + v[2 * i + 1] * w1.y + v[2 * i + 2] * w2.y;
      }
    }
  }
  const int p = oh * WOUT + ow0;
  #pragma unroll
  for (int j = 0; j < 2; ++j) {
    u16x4 o;
    #pragma unroll
    for (int i = 0; i < 4; ++i) o[i] = f2bf(fmaxf(acc[j][i], 0.f));
    *reinterpret_cast<u16x4*>(out + ((size_t)b * OC + oc0 + j) * (WOUT * WOUT) + p) = o;
  }
}

// ---------------- conv2: 64->256, stride 2, relu, + inline pos; writes XT[p][oc]
__global__ __launch_bounds__(256) void conv2_kernel(
    const u16* __restrict__ x1, const float* __restrict__ w,
    const float* __restrict__ bias,
    const float* __restrict__ sp1_w, const float* __restrict__ sp1_b,
    const float* __restrict__ sp2_w, const float* __restrict__ sp2_b,
    u16* __restrict__ xt) {
  constexpr int IC = 64, WIN = 256;
  __shared__ float wl[IC * 9 * 2];
  __shared__ float s1w[128], s1b[64], s2w[128];
  const int tid = threadIdx.x;
  const int oc0 = blockIdx.y * 2;
  const int b = blockIdx.z;
  for (int i = tid; i < IC * 9 * 2; i += 256) {
    int j = (i >= IC * 9) ? 1 : 0;
    int t = i - j * IC * 9;
    wl[t * 2 + j] = w[(size_t)(oc0 + j) * IC * 9 + t];
  }
  if (tid < 128) s1w[tid] = sp1_w[tid];
  if (tid < 64) s1b[tid] = sp1_b[tid];
  if (tid < 128) s2w[tid] = sp2_w[(size_t)(oc0 + (tid >> 6)) * 64 + (tid & 63)];
  __syncthreads();
  const int t = tid & 31;
  const int oh = blockIdx.x * 8 + (tid >> 5);
  const int ow0 = t * 4;
  float acc[2][4];
  #pragma unroll
  for (int j = 0; j < 2; ++j) {
    float bb = bias[oc0 + j];
    #pragma unroll
    for (int i = 0; i < 4; ++i) acc[j][i] = bb;
  }
  for (int ic = 0; ic < IC; ++ic) {
    const u16* plane = x1 + ((size_t)b * IC + ic) * ((size_t)WIN * WIN);
    #pragma unroll
    for (int kh = 0; kh < 3; ++kh) {
      int ih = 2 * oh + kh - 1;
      if ((unsigned)ih >= (unsigned)WIN) continue;
      const u16* row = plane + (size_t)ih * WIN;
      const int base = ow0 * 2;
      float v[9];
      u16x8 a = *reinterpret_cast<const u16x8*>(row + base);
      #pragma unroll
      for (int i2 = 0; i2 < 8; ++i2) v[1 + i2] = bf2f(a[i2]);
      v[0] = (base > 0) ? bf2f(row[base - 1]) : 0.f;
      const float2* wp = reinterpret_cast<const float2*>(wl) + (ic * 3 + kh) * 3;
      float2 w0 = wp[0], w1 = wp[1], w2 = wp[2];
      #pragma unroll
      for (int i = 0; i < 4; ++i) {
        acc[0][i] += v[2 * i] * w0.x + v[2 * i + 1] * w1.x + v[2 * i + 2] * w2.x;
        acc[1][i] += v[2 * i] * w0.y + v[2 * i + 1] * w1.y + v[2 * i + 2] * w2.y;
      }
    }
  }
  // epilogue: relu(conv) + pos(oc, px), scatter into XT[p][oc0..oc0+1]
  const float yy = -1.f + oh * (2.f / 127.f);
  const float sb0 = sp2_b[oc0], sb1 = sp2_b[oc0 + 1];
  u16* xb = xt + (size_t)b * HW * XROW;
  #pragma unroll
  for (int i = 0; i < 4; ++i) {
    float xxv = -1.f + (ow0 + i) * (2.f / 127.f);
    float pa = sb0, pb = sb1;
    #pragma unroll 8
    for (int h = 0; h < 64; ++h) {
      float hid = fmaxf(s1w[2 * h] * xxv + s1w[2 * h + 1] * yy + s1b[h], 0.f);
      pa = fmaf(s2w[h], hid, pa);
      pb = fmaf(s2w[64 + h], hid, pb);
    }
    float r0 = fmaxf(acc[0][i], 0.f) + pa;
    float r1 = fmaxf(acc[1][i], 0.f) + pb;
    int p = oh * 128 + ow0 + i;
    unsigned pk = (unsigned)f2bf(r0) | ((unsigned)f2bf(r1) << 16);
    *reinterpret_cast<unsigned*>(xb + (size_t)p * XROW + oc0) = pk;
  }
}

// ---------------- token pipeline: proj -> gate -> l2norm (f32 out) ----------
__global__ __launch_bounds__(256) void token_kernel(
    const float* __restrict__ tok512, const float* __restrict__ proj_w,
    const float* __restrict__ proj_b, const float* __restrict__ gate_w,
    const float* __restrict__ gate_b, float* __restrict__ tok_out) {
  __shared__ float t512[512];
  __shared__ float prj[256];
  __shared__ float red[4];
  int bl = blockIdx.x;
  int c = threadIdx.x;
  const float* trow = tok512 + (size_t)bl * 512;
  t512[c] = trow[c];
  t512[c + 256] = trow[c + 256];
  __syncthreads();
  float acc = proj_b[c];
  #pragma unroll 4
  for (int k = 0; k < 512; ++k) acc = fmaf(t512[k], proj_w[k * 256 + c], acc);
  prj[c] = acc;
  __syncthreads();
  float acc2 = gate_b[c];
  #pragma unroll 4
  for (int k = 0; k < 256; ++k) acc2 = fmaf(prj[k], gate_w[k * 256 + c], acc2);
  float g = 1.f / (1.f + __expf(-acc2));
  float tv = g * acc;
  float ss = tv * tv;
  #pragma unroll
  for (int off = 1; off < 64; off <<= 1) ss += __shfl_xor(ss, off);
  if ((c & 63) == 0) red[c >> 6] = ss;
  __syncthreads();
  float tot = red[0] + red[1] + red[2] + red[3];
  tok_out[(size_t)bl * 256 + c] = tv * (1.f / fmaxf(sqrtf(tot), 1e-12f));
}

// ---------------- gvec ----------------
__global__ __launch_bounds__(256) void gvec_kernel(
    const float* __restrict__ tok, const int* __restrict__ tokens,
    float* __restrict__ gvec) {
  __shared__ float red[4];
  int b = blockIdx.x, c = threadIdx.x;
  float s = 0.f;
  for (int l = 0; l < LL; ++l) {
    if (tokens[b * LL + l] != 0) s += tok[((size_t)b * LL + l) * 256 + c];
  }
  float ss = s * s;
  #pragma unroll
  for (int off = 1; off < 64; off <<= 1) ss += __shfl_xor(ss, off);
  if ((c & 63) == 0) red[c >> 6] = ss;
  __syncthreads();
  float tot = red[0] + red[1] + red[2] + red[3];
  gvec[b * 256 + c] = s * (1.f / fmaxf(sqrtf(tot), 1e-12f));
}

// ---------------- attn pass 1: scores + softmax -> P (global), sim -> XT ----
// 4 threads per px: thread q owns rows l = 4*li + q -> s[20] only (~80 VGPR).
// Block = 64 px. Softmax reduced over q via shfl_xor(1/2).
__global__ __launch_bounds__(256, 1) void attn_score(
    u16* __restrict__ xt, const float* __restrict__ tok,
    const int* __restrict__ tokens, const float* __restrict__ gvec,
    u16* __restrict__ pg) {
  __shared__ u16 ltok[LL * 256];   // bf16 tokens (39.4 KB)
  __shared__ u16 pl[64 * 104];     // P staging [px][l] (13.3 KB)
  __shared__ float lgv[256];
  __shared__ u16 lval[LL + 3];
  const int tid = threadIdx.x;
  const int b = blockIdx.y;
  const int px0 = blockIdx.x * 64;
  for (int slot = tid; slot < LL * 32; slot += 256) {
    int l = slot >> 5, cg = slot & 31;
    const float* tp = tok + ((size_t)b * LL + l) * 256 + cg * 8;
    float4 t0 = *reinterpret_cast<const float4*>(tp);
    float4 t1 = *reinterpret_cast<const float4*>(tp + 4);
    u16x8 v = {f2bf(t0.x), f2bf(t0.y), f2bf(t0.z), f2bf(t0.w),
               f2bf(t1.x), f2bf(t1.y), f2bf(t1.z), f2bf(t1.w)};
    *reinterpret_cast<u16x8*>(&ltok[l * 256 + cg * 8]) = v;
  }
  // zero P pad columns 77..95 for all 64 rows
  for (int slot = tid; slot < 64 * 19; slot += 256) {
    int row = slot / 19, lp = LL + slot % 19;
    pl[row * 104 + lp] = 0;
  }
  if (tid < LL) lval[tid] = (tokens[b * LL + tid] != 0) ? 1 : 0;
  lgv[tid] = gvec[b * 256 + tid];
  __syncthreads();
  const int pxl = tid >> 2;     // 0..63
  const int q = tid & 3;        // l-phase (lanes 4p+q adjacent in wave)
  const int p = px0 + pxl;
  const u16* xr = xt + ((size_t)b * HW + p) * XROW;
  float s[20];
  #pragma unroll
  for (int i = 0; i < 20; ++i) s[i] = 0.f;
  float ssum = 0.f, simacc = 0.f;
  #pragma unroll 1
  for (int c0 = 0; c0 < 256; c0 += 32) {
    float x[32];
    #pragma unroll
    for (int qq = 0; qq < 4; ++qq) {
      u16x8 iv = *reinterpret_cast<const u16x8*>(xr + c0 + qq * 8);
      #pragma unroll
      for (int k = 0; k < 8; ++k) x[qq * 8 + k] = bf2f(iv[k]);
    }
    #pragma unroll
    for (int k = 0; k < 32; ++k) {
      ssum = fmaf(x[k], x[k], ssum);
      simacc = fmaf(x[k], lgv[c0 + k], simacc);
    }
    #pragma unroll
    for (int li = 0; li < 20; ++li) {
      int l = li * 4 + q;
      if (l < LL) {
        const u16* tr = &ltok[l * 256 + c0];
        float a2 = s[li];
        #pragma unroll
        for (int qq = 0; qq < 4; ++qq) {
          u16x8 tv = *reinterpret_cast<const u16x8*>(tr + qq * 8);
          #pragma unroll
          for (int k = 0; k < 8; ++k) a2 = fmaf(x[qq * 8 + k], bf2f(tv[k]), a2);
        }
        s[li] = a2;
      }
    }
  }
  const float invn = 1.f / fmaxf(sqrtf(ssum), 1e-12f);
  const float sc = invn * 0.0625f;
  float m = -1e30f;
  #pragma unroll
  for (int li = 0; li < 20; ++li) {
    int l = li * 4 + q;
    float v = (l < LL) ? (lval[l] ? s[li] * sc : -10000.f) : -1e30f;
    s[li] = v;
    m = fmaxf(m, v);
  }
  m = fmaxf(m, __shfl_xor(m, 1));
  m = fmaxf(m, __shfl_xor(m, 2));
  float sum = 0.f;
  #pragma unroll
  for (int li = 0; li < 20; ++li) {
    float e = __expf(s[li] - m);   // pad rows: exp(-1e30 - m) = 0
    s[li] = e;
    sum += e;
  }
  sum += __shfl_xor(sum, 1);
  sum += __shfl_xor(sum, 2);
  const float rs = 1.f / sum;
  #pragma unroll
  for (int li = 0; li < 20; ++li) {
    int l = li * 4 + q;
    if (l < LL) pl[pxl * 104 + l] = f2bf(s[li] * rs);
  }
  if (q == 0) {
    u16x8 sv = {f2bf(simacc * invn), 0, 0, 0, 0, 0, 0, 0};
    *reinterpret_cast<u16x8*>(xt + ((size_t)b * HW + p) * XROW + 512) = sv;
  }
  __syncthreads();
  // cooperative P writeout: 64 rows x 96 u16 = 768 x 16B
  u16* pgb = pg + ((size_t)b * HW + px0) * 96;
  #pragma unroll
  for (int it = 0; it < 3; ++it) {
    int slot = it * 256 + tid;
    int row = slot / 12, qq = slot % 12;
    *reinterpret_cast<u16x8*>(pgb + row * 96 + qq * 8) =
        *reinterpret_cast<const u16x8*>(&pl[row * 104 + qq * 8]);
  }
}

// ---------------- attn pass 2: ctx = P @ tok -> XT ctx channels ----------
// P row kept PACKED in 10 u16x8 (40 VGPRs); a[32] per chunk (~90 VGPR total).
__global__ __launch_bounds__(256, 1) void attn_ctx(
    u16* __restrict__ xt, const float* __restrict__ tok,
    const u16* __restrict__ pg) {
  __shared__ u16 ltok[LL * 256];   // bf16 tokens (39.4 KB)
  const int tid = threadIdx.x;
  const int b = blockIdx.y;
  for (int slot = tid; slot < LL * 32; slot += 256) {
    int l = slot >> 5, cg = slot & 31;
    const float* tp = tok + ((size_t)b * LL + l) * 256 + cg * 8;
    float4 t0 = *reinterpret_cast<const float4*>(tp);
    float4 t1 = *reinterpret_cast<const float4*>(tp + 4);
    u16x8 v = {f2bf(t0.x), f2bf(t0.y), f2bf(t0.z), f2bf(t0.w),
               f2bf(t1.x), f2bf(t1.y), f2bf(t1.z), f2bf(t1.w)};
    *reinterpret_cast<u16x8*>(&ltok[l * 256 + cg * 8]) = v;
  }
  __syncthreads();
  const int p = blockIdx.x * 256 + tid;
  const u16* pr = pg + ((size_t)b * HW + p) * 96;
  u16x8 pw[10];   // 80 >= 77 weights, packed bf16
  #pragma unroll
  for (int q = 0; q < 10; ++q)
    pw[q] = *reinterpret_cast<const u16x8*>(pr + q * 8);
  u16* xw = xt + ((size_t)b * HW + p) * XROW + 256;
  #pragma unroll 1
  for (int c0 = 0; c0 < 256; c0 += 32) {
    float a[32];
    #pragma unroll
    for (int k = 0; k < 32; ++k) a[k] = 0.f;
    #pragma unroll
    for (int l = 0; l < LL; ++l) {
      float sl = bf2f(pw[l >> 3][l & 7]);
      const u16* tr = &ltok[l * 256 + c0];
      #pragma unroll
      for (int q = 0; q < 4; ++q) {
        u16x8 tv = *reinterpret_cast<const u16x8*>(tr + q * 8);
        #pragma unroll
        for (int k = 0; k < 8; ++k) a[q * 8 + k] = fmaf(sl, bf2f(tv[k]), a[q * 8 + k]);
      }
    }
    #pragma unroll
    for (int q = 0; q < 4; ++q) {
      u16x8 ov;
      #pragma unroll
      for (int k = 0; k < 8; ++k) ov[k] = f2bf(a[q * 8 + k]);
      *reinterpret_cast<u16x8*>(xw + c0 + q * 8) = ov;
    }
  }
}

// ---------------- MFMA conv 3x3 stride-1 on transposed input ----------------
template <int CHUNKS, int XR, int OC, int OCW, bool AFFINE, bool GNST, bool RELU,
          int OROW>
__global__ __launch_bounds__(256) void convT_mfma(
    const u16* __restrict__ xt, const u16* __restrict__ wt,
    const float* __restrict__ bias, const float* __restrict__ gA,
    const float* __restrict__ gB, float* __restrict__ gnsum,
    u16* __restrict__ outT) {
  constexpr int ICPAD = CHUNKS * 32;
  constexpr int OCB = 4 * OCW;
  constexpr int NOF = OCW / 16;
  __shared__ u16 lb[7920];   // 3*66*5 slots * 8 u16 = 15,840 B
  const int tid = threadIdx.x;
  const int lane = tid & 63;
  const int w = tid >> 6;
  const int oh = blockIdx.x >> 1;
  const int ow0 = (blockIdx.x & 1) << 6;
  const int oc0 = blockIdx.y * OCB + w * OCW;
  const int b = blockIdx.z;
  const int colA = lane & 15;
  const int g = lane >> 4;

  f32x4 acc[NOF][4];
  #pragma unroll
  for (int of = 0; of < NOF; ++of) {
    f32x4 bv;
    #pragma unroll
    for (int r = 0; r < 4; ++r) bv[r] = bias[oc0 + of * 16 + g * 4 + r];
    #pragma unroll
    for (int pf = 0; pf < 4; ++pf) acc[of][pf] = bv;
  }

  const u16* xtb = xt + (size_t)b * HW * XR;
  for (int ch = 0; ch < CHUNKS; ++ch) {
    __syncthreads();
    #pragma unroll
    for (int it = 0; it < 4; ++it) {
      int slot = it * 256 + tid;
      if (slot < 792) {
        int icg = slot & 3;
        int rc = slot >> 2;
        int col = rc % 66;
        int row = rc / 66;
        int ih = oh + row - 1;
        int ip = ow0 - 1 + col;
        int chb = ch * 32 + icg * 8;
        u16x8 v = {0, 0, 0, 0, 0, 0, 0, 0};
        if ((unsigned)ih < 128u && (unsigned)ip < 128u && chb + 8 <= XR) {
          v = *reinterpret_cast<const u16x8*>(xtb + (size_t)(ih * 128 + ip) * XR + chb);
          if constexpr (AFFINE) {
            const float* ga = gA + b * 256 + chb;
            const float* gb2 = gB + b * 256 + chb;
            #pragma unroll
            for (int k = 0; k < 8; ++k)
              v[k] = f2bf(fmaxf(fmaf(bf2f(v[k]), ga[k], gb2[k]), 0.f));
          }
        }
        *reinterpret_cast<u16x8*>(&lb[(rc * 5 + icg) << 3]) = v;
      }
    }
    __syncthreads();
    #pragma unroll
    for (int kk = 0; kk < 9; ++kk) {
      const int kh = kk / 3, kw = kk - kh * 3;
      short8 afrag[NOF];
      const u16* wb = wt + ((size_t)kk * OC + oc0 + colA) * ICPAD + ch * 32 + g * 8;
      #pragma unroll
      for (int of = 0; of < NOF; ++of)
        afrag[of] = *reinterpret_cast<const short8*>(wb + (size_t)of * 16 * ICPAD);
      #pragma unroll
      for (int pf = 0; pf < 4; ++pf) {
        int colx = pf * 16 + colA + kw;
        short8 bfrag = *reinterpret_cast<const short8*>(
            &lb[((kh * 66 + colx) * 5 + g) << 3]);
        #pragma unroll
        for (int of = 0; of < NOF; ++of)
          acc[of][pf] = __builtin_amdgcn_mfma_f32_16x16x32_bf16(
              afrag[of], bfrag, acc[of][pf], 0, 0, 0);
      }
    }
  }
  #pragma unroll
  for (int of = 0; of < NOF; ++of) {
    float s = 0.f, ss = 0.f;
    #pragma unroll
    for (int pf = 0; pf < 4; ++pf) {
      int px = oh * 128 + ow0 + pf * 16 + colA;
      u16x4 o;
      #pragma unroll
      for (int r = 0; r < 4; ++r) {
        float v = acc[of][pf][r];
        if constexpr (RELU) v = fmaxf(v, 0.f);
        if constexpr (GNST) { s += v; ss = fmaf(v, v, ss); }
        o[r] = f2bf(v);
      }
      *reinterpret_cast<u16x4*>(
          outT + ((size_t)b * HW + px) * OROW + oc0 + of * 16 + g * 4) = o;
    }
    if constexpr (GNST) {
      #pragma unroll
      for (int off2 = 1; off2 < 16; off2 <<= 1) {
        s += __shfl_xor(s, off2);
        ss += __shfl_xor(ss, off2);
      }
      s += __shfl_xor(s, 16);
      ss += __shfl_xor(ss, 16);
      if (colA == 0 && (g & 1) == 0) {
        int grp = (oc0 + of * 16 + g * 4) >> 3;
        atomicAdd(gnsum + ((size_t)b * 32 + grp) * 2, s);
        atomicAdd(gnsum + ((size_t)b * 32 + grp) * 2 + 1, ss);
      }
    }
  }
}

// ---------------- GN finalize: sums -> per (b,c) affine a,b ----------------
__global__ __launch_bounds__(256) void gn_fin(
    const float* __restrict__ gnsum, const float* __restrict__ gg,
    const float* __restrict__ gb, float* __restrict__ gA,
    float* __restrict__ gB) {
  int b = blockIdx.x, c = threadIdx.x;
  int grp = c >> 3;
  float s = gnsum[((size_t)b * 32 + grp) * 2];
  float ss = gnsum[((size_t)b * 32 + grp) * 2 + 1];
  float m = s * (1.f / 131072.f);
  float var = ss * (1.f / 131072.f) - m * m;
  float istd = rsqrtf(var + 1e-5f);
  float a = istd * gg[c];
  gA[b * 256 + c] = a;
  gB[b * 256 + c] = gb[c] - m * a;
}

// ---------------- d3: 1x1 conv 64->1 on y2T [p][64] ----------------
__global__ __launch_bounds__(256) void d3_kernel(
    const u16* __restrict__ y2t, const float* __restrict__ w3,
    const float* __restrict__ b3, float* __restrict__ y3) {
  int idx = blockIdx.x * 256 + threadIdx.x;   // 8*16384
  const u16* r = y2t + (size_t)idx * 64;
  float acc = b3[0];
  #pragma unroll
  for (int cg = 0; cg < 8; ++cg) {
    u16x8 v = *reinterpret_cast<const u16x8*>(r + cg * 8);
    #pragma unroll
    for (int k = 0; k < 8; ++k) acc = fmaf(bf2f(v[k]), w3[cg * 8 + k], acc);
  }
  y3[idx] = acc;
}

// ---------------- bilinear upsample 128 -> 512 ----------------
__global__ __launch_bounds__(256) void upsample_kernel(
    const float* __restrict__ y3, float* __restrict__ out) {
  int idx = blockIdx.x * 256 + threadIdx.x;   // 8*512*512
  int b = idx >> 18;
  int rem = idx & 262143;
  int Y = rem >> 9, X = rem & 511;
  float sy = (Y + 0.5f) * 0.25f - 0.5f;
  float sx = (X + 0.5f) * 0.25f - 0.5f;
  float y0f = floorf(sy), x0f = floorf(sx);
  float fy = sy - y0f, fx = sx - x0f;
  int y0 = (int)y0f, x0 = (int)x0f;
  int y0c = max(y0, 0), y1c = min(y0 + 1, 127);
  int x0c = max(x0, 0), x1c = min(x0 + 1, 127);
  const float* yb = y3 + (size_t)b * HW;
  float v00 = yb[y0c * 128 + x0c], v01 = yb[y0c * 128 + x1c];
  float v10 = yb[y1c * 128 + x0c], v11 = yb[y1c * 128 + x1c];
  out[idx] = (1.f - fy) * ((1.f - fx) * v00 + fx * v01) +
             fy * ((1.f - fx) * v10 + fx * v11);
}

extern "C" void kernel_launch(void* const* d_in, const int* in_sizes, int n_in,
                              void* d_out, int out_size, void* d_ws, size_t ws_size,
                              hipStream_t stream) {
  const float* images  = (const float*)d_in[0];
  const int*   tokens  = (const int*)d_in[1];
  const float* tok512  = (const float*)d_in[2];
  const float* conv1_w = (const float*)d_in[3];
  const float* conv1_b = (const float*)d_in[4];
  const float* conv2_w = (const float*)d_in[5];
  const float* conv2_b = (const float*)d_in[6];
  const float* sp1_w   = (const float*)d_in[7];
  const float* sp1_b   = (const float*)d_in[8];
  const float* sp2_w   = (const float*)d_in[9];
  const float* sp2_b   = (const float*)d_in[10];
  const float* proj_w  = (const float*)d_in[11];
  const float* proj_b  = (const float*)d_in[12];
  const float* gate_w  = (const float*)d_in[13];
  const float* gate_b  = (const float*)d_in[14];
  const float* d1_w    = (const float*)d_in[15];
  const float* d1_b    = (const float*)d_in[16];
  const float* gn_g    = (const float*)d_in[17];
  const float* gn_b    = (const float*)d_in[18];
  const float* d2_w    = (const float*)d_in[19];
  const float* d2_b    = (const float*)d_in[20];
  const float* d3_w    = (const float*)d_in[21];
  const float* d3_b    = (const float*)d_in[22];

  float* outp = (float*)d_out;
  if (ws_size < WS_BYTES_NEEDED) {
    float v = 10000.0f + (float)(ws_size >> 20);
    fill_kernel<<<(out_size + 255) / 256, 256, 0, stream>>>(outp, out_size, v);
    return;
  }

  char* wsb = (char*)d_ws;
  u16*   xt    = (u16*)(wsb + OFF_XT);
  u16*   x1    = (u16*)(wsb + OFF_B);
  float* tokb  = (float*)(wsb + OFF_B);            // overlays x1 (dead)
  float* gvecb = (float*)(wsb + OFF_B + OFF_GVECB);
  u16*   pgb   = (u16*)(wsb + OFF_PG);             // P scratch (dead before y1t)
  u16*   y1t   = (u16*)(wsb + OFF_B);              // overlays tokb/P (dead)
  float* gnsum = (float*)(wsb + OFF_GNSUM);
  u16*   y2t   = (u16*)(wsb + OFF_Y2T);            // overlays XT (dead after d1)
  float* gA    = (float*)(wsb + OFF_GA);
  float* gB    = (float*)(wsb + OFF_GB);
  float* y3    = (float*)(wsb + OFF_Y3);

  u16* wt1 = (u16*)d_out;                          // d_out scratch until upsample
  u16* wt2 = (u16*)((char*)d_out + WT1_BYTES);

  prep_wt<<<(9 * 256 * 544 + 255) / 256, 256, 0, stream>>>(
      d1_w, wt1, 256, 513, 544, 9 * 256 * 544);
  prep_wt<<<(9 * 64 * 256 + 255) / 256, 256, 0, stream>>>(
      d2_w, wt2, 64, 256, 256, 9 * 64 * 256);
  zero_gnsum<<<1, 512, 0, stream>>>(gnsum);

  conv1_kernel<<<dim3(64, 32, 8), 256, 0, stream>>>(images, conv1_w, conv1_b, x1);
  conv2_kernel<<<dim3(16, 128, 8), 256, 0, stream>>>(
      x1, conv2_w, conv2_b, sp1_w, sp1_b, sp2_w, sp2_b, xt);
  token_kernel<<<BB * LL, 256, 0, stream>>>(tok512, proj_w, proj_b, gate_w,
                                            gate_b, tokb);
  gvec_kernel<<<BB, 256, 0, stream>>>(tokb, tokens, gvecb);
  attn_score<<<dim3(256, BB), 256, 0, stream>>>(xt, tokb, tokens, gvecb, pgb);
  attn_ctx<<<dim3(64, BB), 256, 0, stream>>>(xt, tokb, pgb);
  // d1: 513->256 MFMA, fused GN stats, out y1T [p][256]
  convT_mfma<17, XROW, 256, 32, false, true, false, 256>
      <<<dim3(256, 2, 8), 256, 0, stream>>>(xt, wt1, d1_b, nullptr, nullptr,
                                            gnsum, y1t);
  gn_fin<<<8, 256, 0, stream>>>(gnsum, gn_g, gn_b, gA, gB);
  // d2: 256->64 MFMA, GN-affine+ReLU fused at staging, ReLU out, y2T [p][64]
  convT_mfma<8, 256, 64, 16, true, false, true, 64>
      <<<dim3(256, 1, 8), 256, 0, stream>>>(y1t, wt2, d2_b, gA, gB, nullptr, y2t);
  d3_kernel<<<512, 256, 0, stream>>>(y2t, d3_w, d3_b, y3);
  upsample_kernel<<<8192, 256, 0, stream>>>(y3, outp);
}

// Round 11
// 1313.846 us; speedup vs baseline: 5.3375x; 1.7908x over previous
//
#include <hip/hip_runtime.h>
#include <math.h>

typedef unsigned short u16;
typedef __attribute__((ext_vector_type(4))) unsigned short u16x4;
typedef __attribute__((ext_vector_type(8))) unsigned short u16x8;
typedef __attribute__((ext_vector_type(8))) short short8;   // MFMA A/B frag (8 bf16)
typedef __attribute__((ext_vector_type(4))) float f32x4;    // MFMA C/D frag

#define BB 8
#define CC 256
#define LL 77
#define HW 16384    // 128*128
#define XROW 520    // XT row stride in ch (513 padded to 8-multiple)

__device__ __forceinline__ float bf2f(u16 h) {
  return __uint_as_float(((unsigned)h) << 16);
}
__device__ __forceinline__ u16 f2bf(float f) {   // round-to-nearest-even
  unsigned u = __float_as_uint(f);
  unsigned r = (u + 0x7fffu + ((u >> 16) & 1u)) >> 16;
  return (u16)r;
}

// ---------------- workspace layout (BYTE offsets) ----------------
// Live intervals (no overlaps):
//   XT   [0, 136314880)            : [pos_xt, d1)
//   x1t  [OFF_B, OFF_B+67.1MB)     : [conv1, conv2]      (region B)
//   tokb/gvec (region B)           : [token, attn_ctx]   (after x1t dead)
//   P    [OFF_PG, +25.2MB)         : [attn_score, attn_ctx]  (after conv2)
//   y1t  (region B)                : [d1, d2)
//   y2t/gA/gB/y3 (region A)        : after d1
static const size_t OFF_XT    = 0;
static const size_t OFF_B     = 136314880;
static const size_t OFF_GVECB = 630784;          // relative to OFF_B
static const size_t OFF_PG    = 137363456;       // P [8][16384][96] bf16 (25.2MB)
static const size_t OFF_GNSUM = 203423744;
static const size_t WS_BYTES_NEEDED = 203425792;  // ~194.0 MiB
// Region-A reuse offsets (absolute):
static const size_t OFF_Y2T = 0;
static const size_t OFF_GA  = 16777216;
static const size_t OFF_GB  = 16785408;
static const size_t OFF_Y3  = 16793600;
// d_out scratch: wt1, wt2, wtc2 (dead until final upsample)
static const size_t WT1_BYTES = 9u * 256u * 544u * 2u;   // 2,506,752
static const size_t WT2_BYTES = 9u * 64u * 256u * 2u;    // 294,912

// ---------------- diagnostic fill (only if ws too small) ----------------
__global__ __launch_bounds__(256) void fill_kernel(float* __restrict__ out,
                                                   int n, float v) {
  int i = blockIdx.x * 256 + threadIdx.x;
  if (i < n) out[i] = v;
}

__global__ __launch_bounds__(512) void zero_gnsum(float* __restrict__ g) {
  g[threadIdx.x] = 0.f;
}

// ---------------- weight transpose: w[oc][ic][3][3] f32 -> wt[kk][oc][icpad] bf16
__global__ __launch_bounds__(256) void prep_wt(
    const float* __restrict__ w, u16* __restrict__ wt,
    int OC, int ICSRC, int ICPAD, int total) {
  int idx = blockIdx.x * 256 + threadIdx.x;
  if (idx >= total) return;
  int ic = idx % ICPAD;
  int oc = (idx / ICPAD) % OC;
  int kk = idx / (ICPAD * OC);
  float v = 0.f;
  if (ic < ICSRC) v = w[((size_t)oc * ICSRC + ic) * 9 + kk];
  wt[idx] = f2bf(v);
}

// ---------------- pos -> XT img channels directly (all 8 batches) ----------
// block = 64 px; thread owns oc-row c=tid (sp2_w row in regs), hid via LDS
// broadcast. conv2_mfma later RMW-adds relu(conv) on top.
__global__ __launch_bounds__(256) void pos_xt(
    const float* __restrict__ sp1_w, const float* __restrict__ sp1_b,
    const float* __restrict__ sp2_w, const float* __restrict__ sp2_b,
    u16* __restrict__ xt) {
  __shared__ float hid[64 * 64];   // [pxl][h] 16 KB
  __shared__ u16 pv[64 * 256];     // [pxl][c] 32 KB
  const int tid = threadIdx.x;
  const int px0 = blockIdx.x * 64;
  // hidden layer: 4096 entries, 16 per thread
  #pragma unroll
  for (int i = 0; i < 16; ++i) {
    int slot = i * 256 + tid;
    int pxl = slot >> 6, h = slot & 63;
    int px = px0 + pxl;
    float xx = -1.f + (px & 127) * (2.f / 127.f);
    float yy = -1.f + (px >> 7) * (2.f / 127.f);
    hid[slot] = fmaxf(sp1_w[2 * h] * xx + sp1_w[2 * h + 1] * yy + sp1_b[h], 0.f);
  }
  // this thread's output-channel weights
  float wr[64];
  #pragma unroll
  for (int q = 0; q < 16; ++q) {
    float4 v = *reinterpret_cast<const float4*>(sp2_w + tid * 64 + q * 4);
    wr[q * 4] = v.x; wr[q * 4 + 1] = v.y; wr[q * 4 + 2] = v.z; wr[q * 4 + 3] = v.w;
  }
  const float sb = sp2_b[tid];
  __syncthreads();
  for (int pxl = 0; pxl < 64; ++pxl) {
    float acc = sb;
    const float* hr = &hid[pxl * 64];
    #pragma unroll
    for (int h = 0; h < 64; ++h) acc = fmaf(wr[h], hr[h], acc);
    pv[pxl * 256 + tid] = f2bf(acc);
  }
  __syncthreads();
  // write to all 8 batches: 64 rows x 256 ch, u16x8 slots
  for (int b = 0; b < BB; ++b) {
    u16* xb = xt + ((size_t)b * HW + px0) * XROW;
    #pragma unroll
    for (int it = 0; it < 8; ++it) {
      int slot = it * 256 + tid;
      int pxl = slot >> 5, cg = slot & 31;
      *reinterpret_cast<u16x8*>(xb + (size_t)pxl * XROW + cg * 8) =
          *reinterpret_cast<const u16x8*>(&pv[pxl * 256 + cg * 8]);
    }
  }
}

// ---------------- conv1: 3->64, stride 2, relu; writes x1T [px][64] ---------
__global__ __launch_bounds__(256) void conv1_kernel(
    const float* __restrict__ in, const float* __restrict__ w,
    const float* __restrict__ bias, u16* __restrict__ x1t) {
  __shared__ float wl[27 * 64];   // [t=(ic*3+kh)*3+kw][oc]
  __shared__ float bl[64];
  const int tid = threadIdx.x;
  const int oh = blockIdx.x;      // 0..255
  const int b = blockIdx.y;
  for (int i = tid; i < 27 * 64; i += 256) {
    int oc = i & 63;
    int t = i >> 6;
    wl[t * 64 + oc] = w[oc * 27 + t];
  }
  if (tid < 64) bl[tid] = bias[tid];
  __syncthreads();
  const int ow = tid;
  float acc[64];
  #pragma unroll
  for (int oc = 0; oc < 64; ++oc) acc[oc] = bl[oc];
  for (int ic = 0; ic < 3; ++ic) {
    #pragma unroll
    for (int kh = 0; kh < 3; ++kh) {
      int ih = 2 * oh + kh - 1;
      if ((unsigned)ih >= 512u) continue;
      const float* row = in + ((size_t)(b * 3 + ic) * 512 + ih) * 512;
      int iw = 2 * ow - 1;
      float v0 = (iw >= 0) ? row[iw] : 0.f;
      float v1 = row[iw + 1];
      float v2 = row[iw + 2];
      const float* wr = &wl[(ic * 3 + kh) * 192];
      #pragma unroll
      for (int oc = 0; oc < 64; ++oc)
        acc[oc] += v0 * wr[oc] + v1 * wr[64 + oc] + v2 * wr[128 + oc];
    }
  }
  u16* orow = x1t + ((size_t)b * 65536 + oh * 256 + ow) * 64;
  #pragma unroll
  for (int q = 0; q < 8; ++q) {
    u16x8 o;
    #pragma unroll
    for (int k = 0; k < 8; ++k) o[k] = f2bf(fmaxf(acc[q * 8 + k], 0.f));
    *reinterpret_cast<u16x8*>(orow + q * 8) = o;
  }
}

// ---------------- conv2 MFMA: 64->256, stride 2; XT[p][oc] += relu(conv) ----
// (XT pre-seeded with pos by pos_xt; ref = relu(conv+bias) + pos.)
__global__ __launch_bounds__(256) void conv2_mfma(
    const u16* __restrict__ x1t, const u16* __restrict__ wt,
    const float* __restrict__ bias, u16* __restrict__ xt) {
  __shared__ u16 lb[15480];   // 1935 slots * 8 u16 = 30,960 B
  const int tid = threadIdx.x;
  const int lane = tid & 63;
  const int w = tid >> 6;
  const int oh = blockIdx.x >> 1;
  const int half = blockIdx.x & 1;
  const int ow0 = half << 6;
  const int b = blockIdx.z;
  const int colA = lane & 15;
  const int g = lane >> 4;
  const int oc0w = w * 64;

  f32x4 acc[4][4];
  #pragma unroll
  for (int of = 0; of < 4; ++of) {
    f32x4 bv;
    #pragma unroll
    for (int r = 0; r < 4; ++r) bv[r] = bias[oc0w + of * 16 + g * 4 + r];
    #pragma unroll
    for (int pf = 0; pf < 4; ++pf) acc[of][pf] = bv;
  }

  const u16* xb = x1t + (size_t)b * 65536 * 64;
  for (int ch = 0; ch < 2; ++ch) {
    __syncthreads();
    // rc<192: even cols (kh*64+i, ip=2*ow0+2i); rc>=192: odd (kh*65+j, ip=2*ow0-1+2j)
    for (int slot = tid; slot < 1548; slot += 256) {
      int icg = slot & 3;
      int rc = slot >> 2;
      int kh, ip;
      if (rc < 192) {
        kh = rc / 64; int i = rc - kh * 64; ip = (ow0 << 1) + 2 * i;
      } else {
        int rc2 = rc - 192; kh = rc2 / 65; int j = rc2 - kh * 65;
        ip = (ow0 << 1) - 1 + 2 * j;
      }
      int ih = 2 * oh + kh - 1;
      u16x8 v = {0, 0, 0, 0, 0, 0, 0, 0};
      if ((unsigned)ih < 256u && (unsigned)ip < 256u)
        v = *reinterpret_cast<const u16x8*>(
            xb + ((size_t)(ih * 256 + ip)) * 64 + ch * 32 + icg * 8);
      *reinterpret_cast<u16x8*>(&lb[(rc * 5 + icg) << 3]) = v;
    }
    __syncthreads();
    #pragma unroll
    for (int kk = 0; kk < 9; ++kk) {
      const int kh = kk / 3, kw = kk - kh * 3;
      short8 afrag[4];
      const u16* wb = wt + ((size_t)kk * 256 + oc0w + colA) * 64 + ch * 32 + g * 8;
      #pragma unroll
      for (int of = 0; of < 4; ++of)
        afrag[of] = *reinterpret_cast<const short8*>(wb + (size_t)of * 16 * 64);
      #pragma unroll
      for (int pf = 0; pf < 4; ++pf) {
        int ow = pf * 16 + colA;
        int rc = (kw == 1) ? (kh * 64 + ow) : (192 + kh * 65 + ow + (kw >> 1));
        short8 bfrag = *reinterpret_cast<const short8*>(&lb[(rc * 5 + g) << 3]);
        #pragma unroll
        for (int of = 0; of < 4; ++of)
          acc[of][pf] = __builtin_amdgcn_mfma_f32_16x16x32_bf16(
              afrag[of], bfrag, acc[of][pf], 0, 0, 0);
      }
    }
  }
  // epilogue: XT[px][oc] = relu(acc) + pos (pre-seeded) — RMW, race-free
  #pragma unroll
  for (int of = 0; of < 4; ++of) {
    #pragma unroll
    for (int pf = 0; pf < 4; ++pf) {
      int px = oh * 128 + ow0 + pf * 16 + colA;
      int oc = oc0w + of * 16 + g * 4;
      u16* dst = xt + ((size_t)b * HW + px) * XROW + oc;
      u16x4 pz = *reinterpret_cast<const u16x4*>(dst);
      u16x4 o;
      #pragma unroll
      for (int r = 0; r < 4; ++r)
        o[r] = f2bf(fmaxf(acc[of][pf][r], 0.f) + bf2f(pz[r]));
      *reinterpret_cast<u16x4*>(dst) = o;
    }
  }
}

// ---------------- token pipeline: proj -> gate -> l2norm (f32 out) ----------
__global__ __launch_bounds__(256) void token_kernel(
    const float* __restrict__ tok512, const float* __restrict__ proj_w,
    const float* __restrict__ proj_b, const float* __restrict__ gate_w,
    const float* __restrict__ gate_b, float* __restrict__ tok_out) {
  __shared__ float t512[512];
  __shared__ float prj[256];
  __shared__ float red[4];
  int bl = blockIdx.x;
  int c = threadIdx.x;
  const float* trow = tok512 + (size_t)bl * 512;
  t512[c] = trow[c];
  t512[c + 256] = trow[c + 256];
  __syncthreads();
  float acc = proj_b[c];
  #pragma unroll 4
  for (int k = 0; k < 512; ++k) acc = fmaf(t512[k], proj_w[k * 256 + c], acc);
  prj[c] = acc;
  __syncthreads();
  float acc2 = gate_b[c];
  #pragma unroll 4
  for (int k = 0; k < 256; ++k) acc2 = fmaf(prj[k], gate_w[k * 256 + c], acc2);
  float g = 1.f / (1.f + __expf(-acc2));
  float tv = g * acc;
  float ss = tv * tv;
  #pragma unroll
  for (int off = 1; off < 64; off <<= 1) ss += __shfl_xor(ss, off);
  if ((c & 63) == 0) red[c >> 6] = ss;
  __syncthreads();
  float tot = red[0] + red[1] + red[2] + red[3];
  tok_out[(size_t)bl * 256 + c] = tv * (1.f / fmaxf(sqrtf(tot), 1e-12f));
}

// ---------------- gvec ----------------
__global__ __launch_bounds__(256) void gvec_kernel(
    const float* __restrict__ tok, const int* __restrict__ tokens,
    float* __restrict__ gvec) {
  __shared__ float red[4];
  int b = blockIdx.x, c = threadIdx.x;
  float s = 0.f;
  for (int l = 0; l < LL; ++l) {
    if (tokens[b * LL + l] != 0) s += tok[((size_t)b * LL + l) * 256 + c];
  }
  float ss = s * s;
  #pragma unroll
  for (int off = 1; off < 64; off <<= 1) ss += __shfl_xor(ss, off);
  if ((c & 63) == 0) red[c >> 6] = ss;
  __syncthreads();
  float tot = red[0] + red[1] + red[2] + red[3];
  gvec[b * 256 + c] = s * (1.f / fmaxf(sqrtf(tot), 1e-12f));
}

// ---------------- attn pass 1: scores + softmax -> P (global), sim -> XT ----
// 4 threads per px: thread q owns rows l = 4*li + q -> s[20] only (~80 VGPR).
__global__ __launch_bounds__(256, 1) void attn_score(
    u16* __restrict__ xt, const float* __restrict__ tok,
    const int* __restrict__ tokens, const float* __restrict__ gvec,
    u16* __restrict__ pg) {
  __shared__ u16 ltok[LL * 256];   // bf16 tokens (39.4 KB)
  __shared__ u16 pl[64 * 104];     // P staging [px][l] (13.3 KB)
  __shared__ float lgv[256];
  __shared__ u16 lval[LL + 3];
  const int tid = threadIdx.x;
  const int b = blockIdx.y;
  const int px0 = blockIdx.x * 64;
  for (int slot = tid; slot < LL * 32; slot += 256) {
    int l = slot >> 5, cg = slot & 31;
    const float* tp = tok + ((size_t)b * LL + l) * 256 + cg * 8;
    float4 t0 = *reinterpret_cast<const float4*>(tp);
    float4 t1 = *reinterpret_cast<const float4*>(tp + 4);
    u16x8 v = {f2bf(t0.x), f2bf(t0.y), f2bf(t0.z), f2bf(t0.w),
               f2bf(t1.x), f2bf(t1.y), f2bf(t1.z), f2bf(t1.w)};
    *reinterpret_cast<u16x8*>(&ltok[l * 256 + cg * 8]) = v;
  }
  for (int slot = tid; slot < 64 * 19; slot += 256) {
    int row = slot / 19, lp = LL + slot % 19;
    pl[row * 104 + lp] = 0;
  }
  if (tid < LL) lval[tid] = (tokens[b * LL + tid] != 0) ? 1 : 0;
  lgv[tid] = gvec[b * 256 + tid];
  __syncthreads();
  const int pxl = tid >> 2;
  const int q = tid & 3;
  const int p = px0 + pxl;
  const u16* xr = xt + ((size_t)b * HW + p) * XROW;
  float s[20];
  #pragma unroll
  for (int i = 0; i < 20; ++i) s[i] = 0.f;
  float ssum = 0.f, simacc = 0.f;
  #pragma unroll 1
  for (int c0 = 0; c0 < 256; c0 += 32) {
    float x[32];
    #pragma unroll
    for (int qq = 0; qq < 4; ++qq) {
      u16x8 iv = *reinterpret_cast<const u16x8*>(xr + c0 + qq * 8);
      #pragma unroll
      for (int k = 0; k < 8; ++k) x[qq * 8 + k] = bf2f(iv[k]);
    }
    #pragma unroll
    for (int k = 0; k < 32; ++k) {
      ssum = fmaf(x[k], x[k], ssum);
      simacc = fmaf(x[k], lgv[c0 + k], simacc);
    }
    #pragma unroll
    for (int li = 0; li < 20; ++li) {
      int l = li * 4 + q;
      if (l < LL) {
        const u16* tr = &ltok[l * 256 + c0];
        float a2 = s[li];
        #pragma unroll
        for (int qq = 0; qq < 4; ++qq) {
          u16x8 tv = *reinterpret_cast<const u16x8*>(tr + qq * 8);
          #pragma unroll
          for (int k = 0; k < 8; ++k) a2 = fmaf(x[qq * 8 + k], bf2f(tv[k]), a2);
        }
        s[li] = a2;
      }
    }
  }
  const float invn = 1.f / fmaxf(sqrtf(ssum), 1e-12f);
  const float sc = invn * 0.0625f;
  float m = -1e30f;
  #pragma unroll
  for (int li = 0; li < 20; ++li) {
    int l = li * 4 + q;
    float v = (l < LL) ? (lval[l] ? s[li] * sc : -10000.f) : -1e30f;
    s[li] = v;
    m = fmaxf(m, v);
  }
  m = fmaxf(m, __shfl_xor(m, 1));
  m = fmaxf(m, __shfl_xor(m, 2));
  float sum = 0.f;
  #pragma unroll
  for (int li = 0; li < 20; ++li) {
    float e = __expf(s[li] - m);
    s[li] = e;
    sum += e;
  }
  sum += __shfl_xor(sum, 1);
  sum += __shfl_xor(sum, 2);
  const float rs = 1.f / sum;
  #pragma unroll
  for (int li = 0; li < 20; ++li) {
    int l = li * 4 + q;
    if (l < LL) pl[pxl * 104 + l] = f2bf(s[li] * rs);
  }
  if (q == 0) {
    u16x8 sv = {f2bf(simacc * invn), 0, 0, 0, 0, 0, 0, 0};
    *reinterpret_cast<u16x8*>(xt + ((size_t)b * HW + p) * XROW + 512) = sv;
  }
  __syncthreads();
  u16* pgb = pg + ((size_t)b * HW + px0) * 96;
  #pragma unroll
  for (int it = 0; it < 3; ++it) {
    int slot = it * 256 + tid;
    int row = slot / 12, qq = slot % 12;
    *reinterpret_cast<u16x8*>(pgb + row * 96 + qq * 8) =
        *reinterpret_cast<const u16x8*>(&pl[row * 104 + qq * 8]);
  }
}

// ---------------- attn pass 2: ctx = P @ tok -> XT ctx channels ----------
__global__ __launch_bounds__(256, 1) void attn_ctx(
    u16* __restrict__ xt, const float* __restrict__ tok,
    const u16* __restrict__ pg) {
  __shared__ u16 ltok[LL * 256];
  const int tid = threadIdx.x;
  const int b = blockIdx.y;
  for (int slot = tid; slot < LL * 32; slot += 256) {
    int l = slot >> 5, cg = slot & 31;
    const float* tp = tok + ((size_t)b * LL + l) * 256 + cg * 8;
    float4 t0 = *reinterpret_cast<const float4*>(tp);
    float4 t1 = *reinterpret_cast<const float4*>(tp + 4);
    u16x8 v = {f2bf(t0.x), f2bf(t0.y), f2bf(t0.z), f2bf(t0.w),
               f2bf(t1.x), f2bf(t1.y), f2bf(t1.z), f2bf(t1.w)};
    *reinterpret_cast<u16x8*>(&ltok[l * 256 + cg * 8]) = v;
  }
  __syncthreads();
  const int p = blockIdx.x * 256 + tid;
  const u16* pr = pg + ((size_t)b * HW + p) * 96;
  u16x8 pw[10];
  #pragma unroll
  for (int q = 0; q < 10; ++q)
    pw[q] = *reinterpret_cast<const u16x8*>(pr + q * 8);
  u16* xw = xt + ((size_t)b * HW + p) * XROW + 256;
  #pragma unroll 1
  for (int c0 = 0; c0 < 256; c0 += 32) {
    float a[32];
    #pragma unroll
    for (int k = 0; k < 32; ++k) a[k] = 0.f;
    #pragma unroll
    for (int l = 0; l < LL; ++l) {
      float sl = bf2f(pw[l >> 3][l & 7]);
      const u16* tr = &ltok[l * 256 + c0];
      #pragma unroll
      for (int q = 0; q < 4; ++q) {
        u16x8 tv = *reinterpret_cast<const u16x8*>(tr + q * 8);
        #pragma unroll
        for (int k = 0; k < 8; ++k) a[q * 8 + k] = fmaf(sl, bf2f(tv[k]), a[q * 8 + k]);
      }
    }
    #pragma unroll
    for (int q = 0; q < 4; ++q) {
      u16x8 ov;
      #pragma unroll
      for (int k = 0; k < 8; ++k) ov[k] = f2bf(a[q * 8 + k]);
      *reinterpret_cast<u16x8*>(xw + c0 + q * 8) = ov;
    }
  }
}

// ---------------- MFMA conv 3x3 stride-1 on transposed input ----------------
template <int CHUNKS, int XR, int OC, int OCW, bool AFFINE, bool GNST, bool RELU,
          int OROW>
__global__ __launch_bounds__(256) void convT_mfma(
    const u16* __restrict__ xt, const u16* __restrict__ wt,
    const float* __restrict__ bias, const float* __restrict__ gA,
    const float* __restrict__ gB, float* __restrict__ gnsum,
    u16* __restrict__ outT) {
  constexpr int ICPAD = CHUNKS * 32;
  constexpr int OCB = 4 * OCW;
  constexpr int NOF = OCW / 16;
  __shared__ u16 lb[7920];
  const int tid = threadIdx.x;
  const int lane = tid & 63;
  const int w = tid >> 6;
  const int oh = blockIdx.x >> 1;
  const int ow0 = (blockIdx.x & 1) << 6;
  const int oc0 = blockIdx.y * OCB + w * OCW;
  const int b = blockIdx.z;
  const int colA = lane & 15;
  const int g = lane >> 4;

  f32x4 acc[NOF][4];
  #pragma unroll
  for (int of = 0; of < NOF; ++of) {
    f32x4 bv;
    #pragma unroll
    for (int r = 0; r < 4; ++r) bv[r] = bias[oc0 + of * 16 + g * 4 + r];
    #pragma unroll
    for (int pf = 0; pf < 4; ++pf) acc[of][pf] = bv;
  }

  const u16* xtb = xt + (size_t)b * HW * XR;
  for (int ch = 0; ch < CHUNKS; ++ch) {
    __syncthreads();
    #pragma unroll
    for (int it = 0; it < 4; ++it) {
      int slot = it * 256 + tid;
      if (slot < 792) {
        int icg = slot & 3;
        int rc = slot >> 2;
        int col = rc % 66;
        int row = rc / 66;
        int ih = oh + row - 1;
        int ip = ow0 - 1 + col;
        int chb = ch * 32 + icg * 8;
        u16x8 v = {0, 0, 0, 0, 0, 0, 0, 0};
        if ((unsigned)ih < 128u && (unsigned)ip < 128u && chb + 8 <= XR) {
          v = *reinterpret_cast<const u16x8*>(xtb + (size_t)(ih * 128 + ip) * XR + chb);
          if constexpr (AFFINE) {
            const float* ga = gA + b * 256 + chb;
            const float* gb2 = gB + b * 256 + chb;
            #pragma unroll
            for (int k = 0; k < 8; ++k)
              v[k] = f2bf(fmaxf(fmaf(bf2f(v[k]), ga[k], gb2[k]), 0.f));
          }
        }
        *reinterpret_cast<u16x8*>(&lb[(rc * 5 + icg) << 3]) = v;
      }
    }
    __syncthreads();
    #pragma unroll
    for (int kk = 0; kk < 9; ++kk) {
      const int kh = kk / 3, kw = kk - kh * 3;
      short8 afrag[NOF];
      const u16* wb = wt + ((size_t)kk * OC + oc0 + colA) * ICPAD + ch * 32 + g * 8;
      #pragma unroll
      for (int of = 0; of < NOF; ++of)
        afrag[of] = *reinterpret_cast<const short8*>(wb + (size_t)of * 16 * ICPAD);
      #pragma unroll
      for (int pf = 0; pf < 4; ++pf) {
        int colx = pf * 16 + colA + kw;
        short8 bfrag = *reinterpret_cast<const short8*>(
            &lb[((kh * 66 + colx) * 5 + g) << 3]);
        #pragma unroll
        for (int of = 0; of < NOF; ++of)
          acc[of][pf] = __builtin_amdgcn_mfma_f32_16x16x32_bf16(
              afrag[of], bfrag, acc[of][pf], 0, 0, 0);
      }
    }
  }
  #pragma unroll
  for (int of = 0; of < NOF; ++of) {
    float s = 0.f, ss = 0.f;
    #pragma unroll
    for (int pf = 0; pf < 4; ++pf) {
      int px = oh * 128 + ow0 + pf * 16 + colA;
      u16x4 o;
      #pragma unroll
      for (int r = 0; r < 4; ++r) {
        float v = acc[of][pf][r];
        if constexpr (RELU) v = fmaxf(v, 0.f);
        if constexpr (GNST) { s += v; ss = fmaf(v, v, ss); }
        o[r] = f2bf(v);
      }
      *reinterpret_cast<u16x4*>(
          outT + ((size_t)b * HW + px) * OROW + oc0 + of * 16 + g * 4) = o;
    }
    if constexpr (GNST) {
      #pragma unroll
      for (int off2 = 1; off2 < 16; off2 <<= 1) {
        s += __shfl_xor(s, off2);
        ss += __shfl_xor(ss, off2);
      }
      s += __shfl_xor(s, 16);
      ss += __shfl_xor(ss, 16);
      if (colA == 0 && (g & 1) == 0) {
        int grp = (oc0 + of * 16 + g * 4) >> 3;
        atomicAdd(gnsum + ((size_t)b * 32 + grp) * 2, s);
        atomicAdd(gnsum + ((size_t)b * 32 + grp) * 2 + 1, ss);
      }
    }
  }
}

// ---------------- GN finalize: sums -> per (b,c) affine a,b ----------------
__global__ __launch_bounds__(256) void gn_fin(
    const float* __restrict__ gnsum, const float* __restrict__ gg,
    const float* __restrict__ gb, float* __restrict__ gA,
    float* __restrict__ gB) {
  int b = blockIdx.x, c = threadIdx.x;
  int grp = c >> 3;
  float s = gnsum[((size_t)b * 32 + grp) * 2];
  float ss = gnsum[((size_t)b * 32 + grp) * 2 + 1];
  float m = s * (1.f / 131072.f);
  float var = ss * (1.f / 131072.f) - m * m;
  float istd = rsqrtf(var + 1e-5f);
  float a = istd * gg[c];
  gA[b * 256 + c] = a;
  gB[b * 256 + c] = gb[c] - m * a;
}

// ---------------- d3: 1x1 conv 64->1 on y2T [p][64] ----------------
__global__ __launch_bounds__(256) void d3_kernel(
    const u16* __restrict__ y2t, const float* __restrict__ w3,
    const float* __restrict__ b3, float* __restrict__ y3) {
  int idx = blockIdx.x * 256 + threadIdx.x;
  const u16* r = y2t + (size_t)idx * 64;
  float acc = b3[0];
  #pragma unroll
  for (int cg = 0; cg < 8; ++cg) {
    u16x8 v = *reinterpret_cast<const u16x8*>(r + cg * 8);
    #pragma unroll
    for (int k = 0; k < 8; ++k) acc = fmaf(bf2f(v[k]), w3[cg * 8 + k], acc);
  }
  y3[idx] = acc;
}

// ---------------- bilinear upsample 128 -> 512 ----------------
__global__ __launch_bounds__(256) void upsample_kernel(
    const float* __restrict__ y3, float* __restrict__ out) {
  int idx = blockIdx.x * 256 + threadIdx.x;
  int b = idx >> 18;
  int rem = idx & 262143;
  int Y = rem >> 9, X = rem & 511;
  float sy = (Y + 0.5f) * 0.25f - 0.5f;
  float sx = (X + 0.5f) * 0.25f - 0.5f;
  float y0f = floorf(sy), x0f = floorf(sx);
  float fy = sy - y0f, fx = sx - x0f;
  int y0 = (int)y0f, x0 = (int)x0f;
  int y0c = max(y0, 0), y1c = min(y0 + 1, 127);
  int x0c = max(x0, 0), x1c = min(x0 + 1, 127);
  const float* yb = y3 + (size_t)b * HW;
  float v00 = yb[y0c * 128 + x0c], v01 = yb[y0c * 128 + x1c];
  float v10 = yb[y1c * 128 + x0c], v11 = yb[y1c * 128 + x1c];
  out[idx] = (1.f - fy) * ((1.f - fx) * v00 + fx * v01) +
             fy * ((1.f - fx) * v10 + fx * v11);
}

extern "C" void kernel_launch(void* const* d_in, const int* in_sizes, int n_in,
                              void* d_out, int out_size, void* d_ws, size_t ws_size,
                              hipStream_t stream) {
  const float* images  = (const float*)d_in[0];
  const int*   tokens  = (const int*)d_in[1];
  const float* tok512  = (const float*)d_in[2];
  const float* conv1_w = (const float*)d_in[3];
  const float* conv1_b = (const float*)d_in[4];
  const float* conv2_w = (const float*)d_in[5];
  const float* conv2_b = (const float*)d_in[6];
  const float* sp1_w   = (const float*)d_in[7];
  const float* sp1_b   = (const float*)d_in[8];
  const float* sp2_w   = (const float*)d_in[9];
  const float* sp2_b   = (const float*)d_in[10];
  const float* proj_w  = (const float*)d_in[11];
  const float* proj_b  = (const float*)d_in[12];
  const float* gate_w  = (const float*)d_in[13];
  const float* gate_b  = (const float*)d_in[14];
  const float* d1_w    = (const float*)d_in[15];
  const float* d1_b    = (const float*)d_in[16];
  const float* gn_g    = (const float*)d_in[17];
  const float* gn_b    = (const float*)d_in[18];
  const float* d2_w    = (const float*)d_in[19];
  const float* d2_b    = (const float*)d_in[20];
  const float* d3_w    = (const float*)d_in[21];
  const float* d3_b    = (const float*)d_in[22];

  float* outp = (float*)d_out;
  if (ws_size < WS_BYTES_NEEDED) {
    float v = 10000.0f + (float)(ws_size >> 20);
    fill_kernel<<<(out_size + 255) / 256, 256, 0, stream>>>(outp, out_size, v);
    return;
  }

  char* wsb = (char*)d_ws;
  u16*   xt    = (u16*)(wsb + OFF_XT);
  u16*   x1t   = (u16*)(wsb + OFF_B);              // x1T [b][65536][64]
  float* tokb  = (float*)(wsb + OFF_B);            // overlays x1t (dead after conv2)
  float* gvecb = (float*)(wsb + OFF_B + OFF_GVECB);
  u16*   pgb   = (u16*)(wsb + OFF_PG);             // P (written after conv2)
  u16*   y1t   = (u16*)(wsb + OFF_B);              // overlays tokb/P
  float* gnsum = (float*)(wsb + OFF_GNSUM);
  u16*   y2t   = (u16*)(wsb + OFF_Y2T);            // overlays XT (dead after d1)
  float* gA    = (float*)(wsb + OFF_GA);
  float* gB    = (float*)(wsb + OFF_GB);
  float* y3    = (float*)(wsb + OFF_Y3);

  u16* wt1  = (u16*)d_out;                         // d_out scratch until upsample
  u16* wt2  = (u16*)((char*)d_out + WT1_BYTES);
  u16* wtc2 = (u16*)((char*)d_out + WT1_BYTES + WT2_BYTES);

  prep_wt<<<(9 * 256 * 544 + 255) / 256, 256, 0, stream>>>(
      d1_w, wt1, 256, 513, 544, 9 * 256 * 544);
  prep_wt<<<(9 * 64 * 256 + 255) / 256, 256, 0, stream>>>(
      d2_w, wt2, 64, 256, 256, 9 * 64 * 256);
  prep_wt<<<(9 * 256 * 64 + 255) / 256, 256, 0, stream>>>(
      conv2_w, wtc2, 256, 64, 64, 9 * 256 * 64);
  zero_gnsum<<<1, 512, 0, stream>>>(gnsum);

  pos_xt<<<256, 256, 0, stream>>>(sp1_w, sp1_b, sp2_w, sp2_b, xt);
  conv1_kernel<<<dim3(256, 8), 256, 0, stream>>>(images, conv1_w, conv1_b, x1t);
  conv2_mfma<<<dim3(256, 1, 8), 256, 0, stream>>>(x1t, wtc2, conv2_b, xt);
  token_kernel<<<BB * LL, 256, 0, stream>>>(tok512, proj_w, proj_b, gate_w,
                                            gate_b, tokb);
  gvec_kernel<<<BB, 256, 0, stream>>>(tokb, tokens, gvecb);
  attn_score<<<dim3(256, BB), 256, 0, stream>>>(xt, tokb, tokens, gvecb, pgb);
  attn_ctx<<<dim3(64, BB), 256, 0, stream>>>(xt, tokb, pgb);
  // d1: 513->256 MFMA, fused GN stats, out y1T [p][256]
  convT_mfma<17, XROW, 256, 32, false, true, false, 256>
      <<<dim3(256, 2, 8), 256, 0, stream>>>(xt, wt1, d1_b, nullptr, nullptr,
                                            gnsum, y1t);
  gn_fin<<<8, 256, 0, stream>>>(gnsum, gn_g, gn_b, gA, gB);
  // d2: 256->64 MFMA, GN-affine+ReLU fused at staging, ReLU out, y2T [p][64]
  convT_mfma<8, 256, 64, 16, true, false, true, 64>
      <<<dim3(256, 1, 8), 256, 0, stream>>>(y1t, wt2, d2_b, gA, gB, nullptr, y2t);
  d3_kernel<<<512, 256, 0, stream>>>(y2t, d3_w, d3_b, y3);
  upsample_kernel<<<8192, 256, 0, stream>>>(y3, outp);
}